// Round 1
// 1015.625 us; speedup vs baseline: 1.0626x; 1.0626x over previous
//
#include <hip/hip_runtime.h>
#include <hip/hip_bf16.h>

// GIN_34789235098229 — round 12: cvt_batch atomic histogram -> sorted boundary scan.
// Round 11 = 1079 us; top-5 dispatches ALL cvt_batch_kernel @76.5us with
// VALUBusy 0.03%, WRITE_SIZE 3.4MB (vs 0.4MB useful): 100k atomicAdd into 512
// addrs, batch sorted => all 64 lanes of a wave hit the SAME address => 64-way
// L2 serialization + atomic write amplification. Fix: batch is sorted, so group
// counts come free from boundary detection: thread i writes gstart[g]=i+1 for
// every g in (b[i], b[i+1]] (each g written exactly once, zero atomics);
// gcnt[g] = gstart[g+1]-gstart[g] computed in invg_kernel. gcnt memset dropped.
// Everything else unchanged from round 11.

typedef unsigned short ushort_t;
typedef unsigned int uint_t;

#define NN 100000
#define EE 3200000
#define GG 512
#define NBK 391    // ceil(NN/256); bucket = node >> 8
#define NHB 256    // histogram blocks
#define ECHUNK 12500  // EE / NHB exactly

// ---------- detection ----------
__global__ __launch_bounds__(256) void detect_kernel(
    const uint_t* __restrict__ xw, const uint_t* __restrict__ ew,
    const uint_t* __restrict__ bw, int* __restrict__ flags)
{
    __shared__ int sb[256], se[256], sbb[256];
    int t = threadIdx.x;
    uint_t w = xw[t];
    uint_t eL = (w >> 7) & 0xffu;
    sb[t] = (eL >= 112u && eL <= 135u) ? 1 : 0;
    se[t] = (ew[2 * t + 1] == 0u) ? 1 : 0;
    sbb[t] = (bw[NN - 512 + 2 * t + 1] == 0u) ? 1 : 0;
    __syncthreads();
    for (int off = 128; off > 0; off >>= 1) {
        if (t < off) { sb[t] += sb[t + off]; se[t] += se[t + off]; sbb[t] += sbb[t + off]; }
        __syncthreads();
    }
    if (t == 0) {
        flags[0] = (sb[0] < 128) ? 1 : 0;   // 1 => fp32 floats
        flags[1] = (se[0] >= 128) ? 1 : 0;  // 1 => int64 edges
        flags[2] = (sbb[0] >= 128) ? 1 : 0; // 1 => int64 batch
    }
}

// ---------- canonicalization ----------
__global__ __launch_bounds__(256) void cvt_w_kernel(
    const void* __restrict__ W1, const void* __restrict__ b1,
    const void* __restrict__ W2, const void* __restrict__ b2,
    const void* __restrict__ g, const void* __restrict__ be,
    const int* __restrict__ flags, float* __restrict__ wf)
{
    int i = blockIdx.x * 256 + threadIdx.x;
    if (i >= 33792) return;
    const void* src; int off;
    if (i < 16384)      { src = W1; off = i; }
    else if (i < 32768) { src = W2; off = i - 16384; }
    else if (i < 33024) { src = b1; off = i - 32768; }
    else if (i < 33280) { src = b2; off = i - 33024; }
    else if (i < 33536) { src = g;  off = i - 33280; }
    else                { src = be; off = i - 33536; }
    float v = flags[0] ? ((const float*)src)[off]
                       : __bfloat162float(((const __hip_bfloat16*)src)[off]);
    wf[i] = v;
}

__global__ __launch_bounds__(256) void cvt_x_kernel(
    const void* __restrict__ x, const int* __restrict__ flags,
    float* __restrict__ zA, ushort_t* __restrict__ zb, int total)
{
    int i = blockIdx.x * 256 + threadIdx.x;
    if (i >= total) return;
    float v;
    ushort_t bits;
    if (flags[0]) {
        v = ((const float*)x)[i];
        __hip_bfloat16 b = __float2bfloat16(v);
        bits = *(ushort_t*)&b;
    } else {
        bits = ((const ushort_t*)x)[i];
        uint_t u = (uint_t)bits << 16;
        v = __uint_as_float(u);
    }
    zA[i] = v;
    zb[i] = bits;
}

// batch is SORTED: zero-atomic group offsets via boundary detection.
// gstart[g] (G+1 entries) = first index i with batch[i] >= g.
__global__ __launch_bounds__(256) void cvt_batch_kernel(
    const int* __restrict__ bw, const int* __restrict__ flags,
    int* __restrict__ b32, int* __restrict__ gstart, int n)
{
    int i = blockIdx.x * 256 + threadIdx.x;
    if (i >= n) return;
    int i64 = flags[2];
    int v = i64 ? bw[2 * i] : bw[i];
    b32[i] = v;
    int vn = (i + 1 < n) ? (i64 ? bw[2 * (i + 1)] : bw[i + 1]) : GG;
    if (i == 0) {
        for (int g = 0; g <= v; ++g) gstart[g] = 0;
    }
    if (vn != v) {
        for (int g = v + 1; g <= vn; ++g) gstart[g] = i + 1;
    }
}

// ---------- atomic-free CSR build (round 9, unchanged) ----------
__global__ __launch_bounds__(256) void count_hist_kernel(
    const int* __restrict__ ei, const int* __restrict__ flags,
    int* __restrict__ histo, int E)
{
    __shared__ int lh[NBK];
    int b = blockIdx.x, t = threadIdx.x;
    for (int j = t; j < NBK; j += 256) lh[j] = 0;
    __syncthreads();
    int i64 = flags[1];
    int e0 = b * ECHUNK, e1 = min(e0 + ECHUNK, E);
    for (int i = e0 + t; i < e1; i += 256) {
        int d = i64 ? ei[2 * (E + i)] : ei[E + i];
        atomicAdd(&lh[d >> 8], 1);
    }
    __syncthreads();
    for (int j = t; j < NBK; j += 256) histo[j * NHB + b] = lh[j];
}

__global__ __launch_bounds__(NHB) void blockscan_kernel(
    int* __restrict__ histo, int* __restrict__ tot)
{
    __shared__ int sd[NHB];
    int j = blockIdx.x, t = threadIdx.x;
    int v = histo[j * NHB + t];
    sd[t] = v;
    __syncthreads();
    #pragma unroll
    for (int off = 1; off < NHB; off <<= 1) {
        int add = (t >= off) ? sd[t - off] : 0;
        __syncthreads();
        sd[t] += add;
        __syncthreads();
    }
    histo[j * NHB + t] = sd[t] - v;
    if (t == NHB - 1) tot[j] = sd[NHB - 1];
}

__global__ __launch_bounds__(512) void bscan_kernel(
    const int* __restrict__ tot, int* __restrict__ bktoff)
{
    __shared__ int sd[512];
    int t = threadIdx.x;
    int v = (t < NBK) ? tot[t] : 0;
    sd[t] = v;
    __syncthreads();
    #pragma unroll
    for (int off = 1; off < 512; off <<= 1) {
        int add = (t >= off) ? sd[t - off] : 0;
        __syncthreads();
        sd[t] += add;
        __syncthreads();
    }
    if (t < NBK) bktoff[t] = sd[t] - v;
    if (t == 511) bktoff[NBK] = sd[511];
}

__global__ __launch_bounds__(256) void pair_scatter_kernel(
    const int* __restrict__ ei, const int* __restrict__ flags,
    const int* __restrict__ histo, const int* __restrict__ bktoff,
    int2* __restrict__ pairs, int E)
{
    __shared__ int cur[NBK];
    int b = blockIdx.x, t = threadIdx.x;
    for (int j = t; j < NBK; j += 256) cur[j] = histo[j * NHB + b] + bktoff[j];
    __syncthreads();
    int i64 = flags[1];
    int e0 = b * ECHUNK, e1 = min(e0 + ECHUNK, E);
    for (int i = e0 + t; i < e1; i += 256) {
        int d = i64 ? ei[2 * (E + i)] : ei[E + i];
        int s = i64 ? ei[2 * i]       : ei[i];
        int p = atomicAdd(&cur[d >> 8], 1);
        pairs[p] = make_int2(d, s);
    }
}

__global__ __launch_bounds__(256) void bucket_deg_kernel(
    const int2* __restrict__ pairs, const int* __restrict__ bktoff,
    int* __restrict__ deg, int N)
{
    __shared__ int cnt[256];
    int j = blockIdx.x, t = threadIdx.x;
    cnt[t] = 0;
    __syncthreads();
    int e0 = bktoff[j], e1 = bktoff[j + 1];
    for (int i = e0 + t; i < e1; i += 256)
        atomicAdd(&cnt[pairs[i].x & 255], 1);
    __syncthreads();
    int idx = j * 256 + t;
    if (idx < N) deg[idx] = cnt[t];
}

__global__ __launch_bounds__(256) void scan1_kernel(
    const int* __restrict__ deg, int* __restrict__ part, int* __restrict__ bsum, int n)
{
    __shared__ int sd[256];
    int t = threadIdx.x;
    int i0 = blockIdx.x * 1024 + t * 4;
    int v0 = 0, v1 = 0, v2 = 0, v3 = 0;
    if (i0 + 3 < n) {
        int4 v = *(const int4*)(deg + i0);
        v0 = v.x; v1 = v.y; v2 = v.z; v3 = v.w;
    } else if (i0 < n) {
        v0 = deg[i0];
        if (i0 + 1 < n) v1 = deg[i0 + 1];
        if (i0 + 2 < n) v2 = deg[i0 + 2];
    }
    int s = v0 + v1 + v2 + v3;
    sd[t] = s;
    __syncthreads();
    #pragma unroll
    for (int off = 1; off < 256; off <<= 1) {
        int add = (t >= off) ? sd[t - off] : 0;
        __syncthreads();
        sd[t] += add;
        __syncthreads();
    }
    int incl = sd[t];
    int e0 = incl - s;
    int p0 = e0 + v0, p1 = p0 + v1, p2 = p1 + v2, p3 = p2 + v3;
    if (i0 < n)     part[i0]     = p0;
    if (i0 + 1 < n) part[i0 + 1] = p1;
    if (i0 + 2 < n) part[i0 + 2] = p2;
    if (i0 + 3 < n) part[i0 + 3] = p3;
    if (t == 255) bsum[blockIdx.x] = incl;
}

__global__ __launch_bounds__(128) void scan2_kernel(int* __restrict__ bsum, int nb)
{
    __shared__ int sd[128];
    int t = threadIdx.x;
    int own = (t < nb) ? bsum[t] : 0;
    sd[t] = own;
    __syncthreads();
    #pragma unroll
    for (int off = 1; off < 128; off <<= 1) {
        int add = (t >= off) ? sd[t - off] : 0;
        __syncthreads();
        sd[t] += add;
        __syncthreads();
    }
    if (t < nb) bsum[t] = sd[t] - own;
}

__global__ __launch_bounds__(256) void scan3_kernel(
    const int* __restrict__ part, const int* __restrict__ bsum,
    const int* __restrict__ deg, int* __restrict__ indptr,
    float* __restrict__ inv_deg, int n)
{
    int i = blockIdx.x * 256 + threadIdx.x;
    if (i >= n) return;
    int val = part[i] + bsum[i >> 10];
    indptr[i + 1] = val;
    int d = deg[i];
    inv_deg[i] = (d > 0) ? 1.0f / (float)d : 0.0f;
    if (i == 0) indptr[0] = 0;
}

// invg from sorted-boundary gstart + identity-init of the BN affine (A=1, C=0)
__global__ __launch_bounds__(512) void invg_kernel(
    const int* __restrict__ gstart, float* __restrict__ invg,
    float* __restrict__ ac, int G)
{
    int g = threadIdx.x;
    if (g < G) {
        int c = gstart[g + 1] - gstart[g];
        invg[g] = (c > 0) ? 1.0f / (float)c : 0.0f;
    }
    if (g < 64) ac[g] = 1.0f;
    else if (g < 128) ac[g] = 0.0f;
}

__global__ __launch_bounds__(256) void csr_fill_kernel(
    const int2* __restrict__ pairs, const int* __restrict__ bktoff,
    const int* __restrict__ indptr, int* __restrict__ esrc, int N)
{
    __shared__ int cur[256];
    int j = blockIdx.x, t = threadIdx.x;
    int idx = j * 256 + t;
    cur[t] = (idx < N) ? indptr[idx] : 0;
    __syncthreads();
    int e0 = bktoff[j], e1 = bktoff[j + 1];
    for (int i = e0 + t; i < e1; i += 256) {
        int2 e = pairs[i];
        int p = atomicAdd(&cur[e.x & 255], 1);
        esrc[p] = e.y;
    }
}

// ---------- per-layer ----------
// agg (round 10, unchanged): edge-index broadcast + unrolled gathers,
// zout = A*(z_own + mean(z_nb)) + C*(1+[deg>0])
__global__ __launch_bounds__(256) void agg_kernel(
    const float* __restrict__ zprev, const ushort_t* __restrict__ zb,
    const int* __restrict__ indptr, const int* __restrict__ esrc,
    const float* __restrict__ inv_deg, const float* __restrict__ ac,
    float* __restrict__ zout, int n)
{
    int t = threadIdx.x;
    int grp = t >> 4, l = t & 15;
    int lane = t & 63;
    int gl0 = lane & 48;
    int node = blockIdx.x * 16 + grp;
    if (node >= n) return;
    int e0 = indptr[node], e1 = indptr[node + 1];
    float a0 = 0.f, a1 = 0.f, a2 = 0.f, a3 = 0.f;
    const ushort_t* zbl = zb + l * 4;
    for (int base = e0; base < e1; base += 16) {
        int cnt = e1 - base;
        if (cnt > 16) cnt = 16;
        int myi = (l < cnt) ? esrc[base + l] : 0;
        if (cnt == 16) {
            #pragma unroll
            for (int j = 0; j < 16; ++j) {
                int s = __shfl(myi, gl0 + j, 64);
                uint2 v = *(const uint2*)(zbl + (size_t)s * 64);
                a0 += __uint_as_float(v.x << 16);
                a1 += __uint_as_float(v.x & 0xffff0000u);
                a2 += __uint_as_float(v.y << 16);
                a3 += __uint_as_float(v.y & 0xffff0000u);
            }
        } else {
            for (int j = 0; j < cnt; ++j) {
                int s = __shfl(myi, gl0 + j, 64);
                uint2 v = *(const uint2*)(zbl + (size_t)s * 64);
                a0 += __uint_as_float(v.x << 16);
                a1 += __uint_as_float(v.x & 0xffff0000u);
                a2 += __uint_as_float(v.y << 16);
                a3 += __uint_as_float(v.y & 0xffff0000u);
            }
        }
    }
    float idg = inv_deg[node];
    float cf = (idg > 0.f) ? 2.f : 1.f;
    float4 own = *(const float4*)(zprev + (size_t)node * 64 + l * 4);
    float4 A = *(const float4*)(ac + l * 4);
    float4 C = *(const float4*)(ac + 64 + l * 4);
    float4 r;
    r.x = fmaf(A.x, fmaf(idg, a0, own.x), C.x * cf);
    r.y = fmaf(A.y, fmaf(idg, a1, own.y), C.y * cf);
    r.z = fmaf(A.z, fmaf(idg, a2, own.z), C.z * cf);
    r.w = fmaf(A.w, fmaf(idg, a3, own.w), C.w * cf);
    *(float4*)(zout + (size_t)node * 64 + l * 4) = r;
}

// MLP: 4 lanes per node, each owns 16 features. Shared operands broadcast
// via __shfl within the 4-lane group; same k-order FMA chain as round 10.
__global__ __launch_bounds__(256, 2) void mlp_kernel(
    float* __restrict__ zf, ushort_t* __restrict__ zb,
    const float* __restrict__ W1f, const float* __restrict__ b1f,
    const float* __restrict__ W2f, const float* __restrict__ b2f,
    int n)
{
    __shared__ float w1s[4096];
    __shared__ float w2s[4096];
    __shared__ float bs[128];
    int t = threadIdx.x;
    for (int i = t; i < 4096; i += 256) {
        w1s[i] = W1f[i];
        w2s[i] = W2f[i];
    }
    if (t < 64) bs[t] = b1f[t];
    else if (t < 128) bs[t] = b2f[t - 64];
    __syncthreads();

    int idx = blockIdx.x * 256 + t;
    int node = idx >> 2;
    if (node >= n) return;
    int sub = t & 3;
    int lane = t & 63;
    int grp = lane & ~3;          // base lane of my 4-lane group
    int j0 = sub * 16;
    float* zrow = zf + (size_t)node * 64;
    ushort_t* zbrow = zb + (size_t)node * 64;

    // my quarter of z
    float zc[16];
    {
        const float4* zp = (const float4*)(zrow + j0);
        #pragma unroll
        for (int q = 0; q < 4; ++q) {
            float4 v = zp[q];
            zc[4*q] = v.x; zc[4*q+1] = v.y; zc[4*q+2] = v.z; zc[4*q+3] = v.w;
        }
    }

    // GEMM1: y[j0..j0+16)
    float y[16];
    #pragma unroll
    for (int q = 0; q < 16; ++q) y[q] = bs[j0 + q];
    #pragma unroll
    for (int k = 0; k < 64; ++k) {
        float a = __shfl(zc[k & 15], grp + (k >> 4), 64);
        const float4* w = (const float4*)(w1s + k * 64 + j0);
        #pragma unroll
        for (int q = 0; q < 4; ++q) {
            float4 wv = w[q];
            y[4*q]   = fmaf(a, wv.x, y[4*q]);
            y[4*q+1] = fmaf(a, wv.y, y[4*q+1]);
            y[4*q+2] = fmaf(a, wv.z, y[4*q+2]);
            y[4*q+3] = fmaf(a, wv.w, y[4*q+3]);
        }
    }
    #pragma unroll
    for (int q = 0; q < 16; ++q) y[q] = fmaxf(y[q], 0.f);

    // GEMM2: o[j0..j0+16)
    float o[16];
    #pragma unroll
    for (int q = 0; q < 16; ++q) o[q] = bs[64 + j0 + q];
    #pragma unroll
    for (int k = 0; k < 64; ++k) {
        float a = __shfl(y[k & 15], grp + (k >> 4), 64);
        const float4* w = (const float4*)(w2s + k * 64 + j0);
        #pragma unroll
        for (int q = 0; q < 4; ++q) {
            float4 wv = w[q];
            o[4*q]   = fmaf(a, wv.x, o[4*q]);
            o[4*q+1] = fmaf(a, wv.y, o[4*q+1]);
            o[4*q+2] = fmaf(a, wv.z, o[4*q+2]);
            o[4*q+3] = fmaf(a, wv.w, o[4*q+3]);
        }
    }

    // relu + store fp32 + bf16 mirror (group-contiguous)
    #pragma unroll
    for (int q = 0; q < 4; ++q) {
        float4 v;
        v.x = fmaxf(o[4*q],   0.f);
        v.y = fmaxf(o[4*q+1], 0.f);
        v.z = fmaxf(o[4*q+2], 0.f);
        v.w = fmaxf(o[4*q+3], 0.f);
        *(float4*)(zrow + j0 + q * 4) = v;
        __hip_bfloat16 p0 = __float2bfloat16(v.x);
        __hip_bfloat16 p1 = __float2bfloat16(v.y);
        __hip_bfloat16 p2 = __float2bfloat16(v.z);
        __hip_bfloat16 p3 = __float2bfloat16(v.w);
        uint2 pw;
        pw.x = (uint_t)*(ushort_t*)&p0 | ((uint_t)*(ushort_t*)&p1 << 16);
        pw.y = (uint_t)*(ushort_t*)&p2 | ((uint_t)*(ushort_t*)&p3 << 16);
        *(uint2*)(zbrow + j0 + q * 4) = pw;
    }
}

// per-feature sum / sumsq -> float atomics (128 addresses)
__global__ __launch_bounds__(256) void stats_kernel(
    const float* __restrict__ z, float* __restrict__ stats, int N)
{
    __shared__ float ssum[256], ssq[256];
    int t = threadIdx.x;
    float s = 0.f, q = 0.f;
    int total = N * 64;
    for (int i = blockIdx.x * 256 + t; i < total; i += 256 * gridDim.x) {
        float v = z[i];
        s += v;
        q += v * v;
    }
    ssum[t] = s; ssq[t] = q;
    __syncthreads();
    if (t < 64) {
        float S = ssum[t] + ssum[t+64] + ssum[t+128] + ssum[t+192];
        float Q = ssq[t]  + ssq[t+64]  + ssq[t+128]  + ssq[t+192];
        atomicAdd(&stats[t], S);
        atomicAdd(&stats[64 + t], Q);
    }
}

__global__ __launch_bounds__(64) void bnfin_kernel(
    const float* __restrict__ stats, const float* __restrict__ gammaf,
    const float* __restrict__ betaf, float* __restrict__ ac, int N)
{
    int f = threadIdx.x;
    if (f >= 64) return;
    float invN = 1.0f / (float)N;
    float mu = stats[f] * invN;
    float var = stats[64 + f] * invN - mu * mu;
    if (var < 0.f) var = 0.f;
    float inv = rsqrtf(var + 1e-5f);
    float A = gammaf[f] * inv;
    float C = betaf[f] - mu * A;
    ac[f] = A;
    ac[64 + f] = C;
}

// pools only: h = A*z + C on the fly; node_pool (+=), gpool run-length atomics
__global__ __launch_bounds__(256) void pool_kernel(
    const float* __restrict__ z, float* __restrict__ node_pool,
    const int* __restrict__ b32, const float* __restrict__ ac,
    float* __restrict__ gpool, int N, int first)
{
    int wave = (blockIdx.x * 256 + threadIdx.x) >> 6;
    int f = threadIdx.x & 63;
    int n0 = wave * 64;
    if (n0 >= N) return;
    int n1 = min(n0 + 64, N);
    float A = ac[f], C = ac[64 + f];
    float racc = 0.f;
    int cur = b32[n0];
    for (int n = n0; n < n1; ++n) {
        int g = b32[n];
        if (g != cur) {  // wave-uniform branch
            atomicAdd(&gpool[(size_t)cur * 64 + f], racc);
            racc = 0.f;
            cur = g;
        }
        size_t idx = (size_t)n * 64 + f;
        float hv = fmaf(z[idx], A, C);
        float np = first ? hv : (node_pool[idx] + hv);
        node_pool[idx] = np;
        racc += hv;
    }
    atomicAdd(&gpool[(size_t)cur * 64 + f], racc);
}

__global__ __launch_bounds__(256) void finalize_kernel(
    const float* __restrict__ node_pool, const float* __restrict__ gpool,
    const float* __restrict__ invg, const int* __restrict__ flags,
    void* __restrict__ out, int N)
{
    int i = blockIdx.x * 256 + threadIdx.x;
    int nd = N * 64;
    int total = nd + GG * 64;
    if (i >= total) return;
    float v;
    if (i < nd) v = node_pool[i];
    else { int j = i - nd; v = gpool[j] * invg[j >> 6]; }
    if (flags[0]) ((float*)out)[i] = v;
    else ((__hip_bfloat16*)out)[i] = __float2bfloat16(v);
}

extern "C" void kernel_launch(void* const* d_in, const int* in_sizes, int n_in,
                              void* d_out, int out_size, void* d_ws, size_t ws_size,
                              hipStream_t stream)
{
    constexpr int N = NN, E = EE, G = GG;
    constexpr int ND = N * 64;

    const void* x     = d_in[0];
    const void* W1    = d_in[1];
    const void* b1    = d_in[2];
    const void* W2    = d_in[3];
    const void* b2    = d_in[4];
    const void* gamma = d_in[5];
    const void* beta  = d_in[6];
    const int* ei     = (const int*)d_in[7];
    const int* batw   = (const int*)d_in[8];

    char* p = (char*)d_ws;
    auto alloc = [&](size_t bytes) -> char* {
        char* r = p;
        p += (bytes + 255) & ~(size_t)255;
        return r;
    };
    float*    zbufA     = (float*)alloc((size_t)ND * 4);
    float*    zbufB     = (float*)alloc((size_t)ND * 4);
    float*    node_pool = (float*)alloc((size_t)ND * 4);
    ushort_t* zb        = (ushort_t*)alloc((size_t)ND * 2);
    int*      esrc      = (int*)alloc((size_t)E * 4);
    int*      indptr    = (int*)alloc((size_t)(N + 1) * 4);
    int*      deg       = (int*)alloc((size_t)N * 4);
    int*      part      = (int*)alloc((size_t)N * 4);
    float*    invdeg    = (float*)alloc((size_t)N * 4);
    int*      b32       = (int*)alloc((size_t)N * 4);
    int*      bsum      = (int*)alloc(128 * 4);
    int*      gstart    = (int*)alloc((size_t)(G + 1) * 4);
    float*    invg      = (float*)alloc(G * 4);
    float*    gpool     = (float*)alloc((size_t)G * 64 * 4);
    float*    stats     = (float*)alloc(128 * 4);
    float*    ac        = (float*)alloc(128 * 4);
    float*    wf        = (float*)alloc(33792 * 4);
    int*      flags     = (int*)alloc(16 * 4);
    int*      histo     = (int*)alloc((size_t)NBK * NHB * 4);
    int*      tot       = (int*)alloc((size_t)NBK * 4);
    int*      bktoff    = (int*)alloc((size_t)(NBK + 1) * 4);
    // pairs aliases node_pool: dead until first pool_kernel; E*8 == ND*4 bytes
    int2*     pairs     = (int2*)node_pool;

    hipMemsetAsync(gpool, 0, (size_t)G * 64 * 4, stream);

    detect_kernel<<<1, 256, 0, stream>>>(
        (const uint_t*)x, (const uint_t*)ei, (const uint_t*)batw, flags);
    cvt_w_kernel<<<132, 256, 0, stream>>>(W1, b1, W2, b2, gamma, beta, flags, wf);
    cvt_x_kernel<<<(ND + 255) / 256, 256, 0, stream>>>(x, flags, zbufA, zb, ND);
    cvt_batch_kernel<<<(N + 255) / 256, 256, 0, stream>>>(batw, flags, b32, gstart, N);
    count_hist_kernel<<<NHB, 256, 0, stream>>>(ei, flags, histo, E);
    blockscan_kernel<<<NBK, NHB, 0, stream>>>(histo, tot);
    bscan_kernel<<<1, 512, 0, stream>>>(tot, bktoff);
    pair_scatter_kernel<<<NHB, 256, 0, stream>>>(ei, flags, histo, bktoff, pairs, E);
    bucket_deg_kernel<<<NBK, 256, 0, stream>>>(pairs, bktoff, deg, N);
    int nb = (N + 1023) / 1024;  // 98
    scan1_kernel<<<nb, 256, 0, stream>>>(deg, part, bsum, N);
    scan2_kernel<<<1, 128, 0, stream>>>(bsum, nb);
    scan3_kernel<<<(N + 255) / 256, 256, 0, stream>>>(part, bsum, deg, indptr, invdeg, N);
    invg_kernel<<<1, 512, 0, stream>>>(gstart, invg, ac, G);
    csr_fill_kernel<<<NBK, 256, 0, stream>>>(pairs, bktoff, indptr, esrc, N);

    float* zin = zbufA;
    float* zout = zbufB;
    for (int l = 0; l < 4; ++l) {
        agg_kernel<<<(N + 15) / 16, 256, 0, stream>>>(
            zin, zb, indptr, esrc, invdeg, ac, zout, N);
        mlp_kernel<<<(N * 4 + 255) / 256, 256, 0, stream>>>(
            zout, zb, wf + l * 4096, wf + 32768 + l * 64,
            wf + 16384 + l * 4096, wf + 33024 + l * 64, N);
        hipMemsetAsync(stats, 0, 128 * 4, stream);
        stats_kernel<<<256, 256, 0, stream>>>(zout, stats, N);
        bnfin_kernel<<<1, 64, 0, stream>>>(
            stats, wf + 33280 + l * 64, wf + 33536 + l * 64, ac, N);
        pool_kernel<<<(N + 255) / 256, 256, 0, stream>>>(
            zout, node_pool, b32, ac, gpool, N, (l == 0) ? 1 : 0);
        float* tmp = zin; zin = zout; zout = tmp;
    }
    finalize_kernel<<<(ND + G * 64 + 255) / 256, 256, 0, stream>>>(
        node_pool, gpool, invg, flags, d_out, N);
}

// Round 2
// 977.276 us; speedup vs baseline: 1.1043x; 1.0392x over previous
//
#include <hip/hip_runtime.h>
#include <hip/hip_bf16.h>

// GIN_34789235098229 — round 13: agg gather MLP-depth fix (explicit 16-deep ILP).
// Round 12 = 1015.6 us; top-4 = agg_kernel @65.4us x4: hbm 38%, VALU 33%,
// MfmaUtil 0 => latency-bound, neither pipe saturated. VGPR_Count=36 proves the
// compiler can't keep the 16-gather chunk in flight (needs 32 dest VGPRs), and
// the dynamic remainder loop (~7.7 edges/node avg) serializes gather latency.
// Fix: (a) full chunks gather into explicit uint2 vv[16] (issue loop separate
// from accumulate loop, fully unrolled => 16 outstanding loads); (b) remainder
// is a masked 16-wide batch (pad lanes reload edge-0's row = L1 hit, cndmask'd
// to +0.0f => bit-identical accumulation); (c) own/A/C/inv_deg hoisted above
// the edge loop. VGPR ~72 (7 waves/SIMD), trades occupancy for 2-4x MLP.
// Everything else unchanged from round 12.

typedef unsigned short ushort_t;
typedef unsigned int uint_t;

#define NN 100000
#define EE 3200000
#define GG 512
#define NBK 391    // ceil(NN/256); bucket = node >> 8
#define NHB 256    // histogram blocks
#define ECHUNK 12500  // EE / NHB exactly

// ---------- detection ----------
__global__ __launch_bounds__(256) void detect_kernel(
    const uint_t* __restrict__ xw, const uint_t* __restrict__ ew,
    const uint_t* __restrict__ bw, int* __restrict__ flags)
{
    __shared__ int sb[256], se[256], sbb[256];
    int t = threadIdx.x;
    uint_t w = xw[t];
    uint_t eL = (w >> 7) & 0xffu;
    sb[t] = (eL >= 112u && eL <= 135u) ? 1 : 0;
    se[t] = (ew[2 * t + 1] == 0u) ? 1 : 0;
    sbb[t] = (bw[NN - 512 + 2 * t + 1] == 0u) ? 1 : 0;
    __syncthreads();
    for (int off = 128; off > 0; off >>= 1) {
        if (t < off) { sb[t] += sb[t + off]; se[t] += se[t + off]; sbb[t] += sbb[t + off]; }
        __syncthreads();
    }
    if (t == 0) {
        flags[0] = (sb[0] < 128) ? 1 : 0;   // 1 => fp32 floats
        flags[1] = (se[0] >= 128) ? 1 : 0;  // 1 => int64 edges
        flags[2] = (sbb[0] >= 128) ? 1 : 0; // 1 => int64 batch
    }
}

// ---------- canonicalization ----------
__global__ __launch_bounds__(256) void cvt_w_kernel(
    const void* __restrict__ W1, const void* __restrict__ b1,
    const void* __restrict__ W2, const void* __restrict__ b2,
    const void* __restrict__ g, const void* __restrict__ be,
    const int* __restrict__ flags, float* __restrict__ wf)
{
    int i = blockIdx.x * 256 + threadIdx.x;
    if (i >= 33792) return;
    const void* src; int off;
    if (i < 16384)      { src = W1; off = i; }
    else if (i < 32768) { src = W2; off = i - 16384; }
    else if (i < 33024) { src = b1; off = i - 32768; }
    else if (i < 33280) { src = b2; off = i - 33024; }
    else if (i < 33536) { src = g;  off = i - 33280; }
    else                { src = be; off = i - 33536; }
    float v = flags[0] ? ((const float*)src)[off]
                       : __bfloat162float(((const __hip_bfloat16*)src)[off]);
    wf[i] = v;
}

__global__ __launch_bounds__(256) void cvt_x_kernel(
    const void* __restrict__ x, const int* __restrict__ flags,
    float* __restrict__ zA, ushort_t* __restrict__ zb, int total)
{
    int i = blockIdx.x * 256 + threadIdx.x;
    if (i >= total) return;
    float v;
    ushort_t bits;
    if (flags[0]) {
        v = ((const float*)x)[i];
        __hip_bfloat16 b = __float2bfloat16(v);
        bits = *(ushort_t*)&b;
    } else {
        bits = ((const ushort_t*)x)[i];
        uint_t u = (uint_t)bits << 16;
        v = __uint_as_float(u);
    }
    zA[i] = v;
    zb[i] = bits;
}

// batch is SORTED: zero-atomic group offsets via boundary detection.
// gstart[g] (G+1 entries) = first index i with batch[i] >= g.
__global__ __launch_bounds__(256) void cvt_batch_kernel(
    const int* __restrict__ bw, const int* __restrict__ flags,
    int* __restrict__ b32, int* __restrict__ gstart, int n)
{
    int i = blockIdx.x * 256 + threadIdx.x;
    if (i >= n) return;
    int i64 = flags[2];
    int v = i64 ? bw[2 * i] : bw[i];
    b32[i] = v;
    int vn = (i + 1 < n) ? (i64 ? bw[2 * (i + 1)] : bw[i + 1]) : GG;
    if (i == 0) {
        for (int g = 0; g <= v; ++g) gstart[g] = 0;
    }
    if (vn != v) {
        for (int g = v + 1; g <= vn; ++g) gstart[g] = i + 1;
    }
}

// ---------- atomic-free CSR build (round 9, unchanged) ----------
__global__ __launch_bounds__(256) void count_hist_kernel(
    const int* __restrict__ ei, const int* __restrict__ flags,
    int* __restrict__ histo, int E)
{
    __shared__ int lh[NBK];
    int b = blockIdx.x, t = threadIdx.x;
    for (int j = t; j < NBK; j += 256) lh[j] = 0;
    __syncthreads();
    int i64 = flags[1];
    int e0 = b * ECHUNK, e1 = min(e0 + ECHUNK, E);
    for (int i = e0 + t; i < e1; i += 256) {
        int d = i64 ? ei[2 * (E + i)] : ei[E + i];
        atomicAdd(&lh[d >> 8], 1);
    }
    __syncthreads();
    for (int j = t; j < NBK; j += 256) histo[j * NHB + b] = lh[j];
}

__global__ __launch_bounds__(NHB) void blockscan_kernel(
    int* __restrict__ histo, int* __restrict__ tot)
{
    __shared__ int sd[NHB];
    int j = blockIdx.x, t = threadIdx.x;
    int v = histo[j * NHB + t];
    sd[t] = v;
    __syncthreads();
    #pragma unroll
    for (int off = 1; off < NHB; off <<= 1) {
        int add = (t >= off) ? sd[t - off] : 0;
        __syncthreads();
        sd[t] += add;
        __syncthreads();
    }
    histo[j * NHB + t] = sd[t] - v;
    if (t == NHB - 1) tot[j] = sd[NHB - 1];
}

__global__ __launch_bounds__(512) void bscan_kernel(
    const int* __restrict__ tot, int* __restrict__ bktoff)
{
    __shared__ int sd[512];
    int t = threadIdx.x;
    int v = (t < NBK) ? tot[t] : 0;
    sd[t] = v;
    __syncthreads();
    #pragma unroll
    for (int off = 1; off < 512; off <<= 1) {
        int add = (t >= off) ? sd[t - off] : 0;
        __syncthreads();
        sd[t] += add;
        __syncthreads();
    }
    if (t < NBK) bktoff[t] = sd[t] - v;
    if (t == 511) bktoff[NBK] = sd[511];
}

__global__ __launch_bounds__(256) void pair_scatter_kernel(
    const int* __restrict__ ei, const int* __restrict__ flags,
    const int* __restrict__ histo, const int* __restrict__ bktoff,
    int2* __restrict__ pairs, int E)
{
    __shared__ int cur[NBK];
    int b = blockIdx.x, t = threadIdx.x;
    for (int j = t; j < NBK; j += 256) cur[j] = histo[j * NHB + b] + bktoff[j];
    __syncthreads();
    int i64 = flags[1];
    int e0 = b * ECHUNK, e1 = min(e0 + ECHUNK, E);
    for (int i = e0 + t; i < e1; i += 256) {
        int d = i64 ? ei[2 * (E + i)] : ei[E + i];
        int s = i64 ? ei[2 * i]       : ei[i];
        int p = atomicAdd(&cur[d >> 8], 1);
        pairs[p] = make_int2(d, s);
    }
}

__global__ __launch_bounds__(256) void bucket_deg_kernel(
    const int2* __restrict__ pairs, const int* __restrict__ bktoff,
    int* __restrict__ deg, int N)
{
    __shared__ int cnt[256];
    int j = blockIdx.x, t = threadIdx.x;
    cnt[t] = 0;
    __syncthreads();
    int e0 = bktoff[j], e1 = bktoff[j + 1];
    for (int i = e0 + t; i < e1; i += 256)
        atomicAdd(&cnt[pairs[i].x & 255], 1);
    __syncthreads();
    int idx = j * 256 + t;
    if (idx < N) deg[idx] = cnt[t];
}

__global__ __launch_bounds__(256) void scan1_kernel(
    const int* __restrict__ deg, int* __restrict__ part, int* __restrict__ bsum, int n)
{
    __shared__ int sd[256];
    int t = threadIdx.x;
    int i0 = blockIdx.x * 1024 + t * 4;
    int v0 = 0, v1 = 0, v2 = 0, v3 = 0;
    if (i0 + 3 < n) {
        int4 v = *(const int4*)(deg + i0);
        v0 = v.x; v1 = v.y; v2 = v.z; v3 = v.w;
    } else if (i0 < n) {
        v0 = deg[i0];
        if (i0 + 1 < n) v1 = deg[i0 + 1];
        if (i0 + 2 < n) v2 = deg[i0 + 2];
    }
    int s = v0 + v1 + v2 + v3;
    sd[t] = s;
    __syncthreads();
    #pragma unroll
    for (int off = 1; off < 256; off <<= 1) {
        int add = (t >= off) ? sd[t - off] : 0;
        __syncthreads();
        sd[t] += add;
        __syncthreads();
    }
    int incl = sd[t];
    int e0 = incl - s;
    int p0 = e0 + v0, p1 = p0 + v1, p2 = p1 + v2, p3 = p2 + v3;
    if (i0 < n)     part[i0]     = p0;
    if (i0 + 1 < n) part[i0 + 1] = p1;
    if (i0 + 2 < n) part[i0 + 2] = p2;
    if (i0 + 3 < n) part[i0 + 3] = p3;
    if (t == 255) bsum[blockIdx.x] = incl;
}

__global__ __launch_bounds__(128) void scan2_kernel(int* __restrict__ bsum, int nb)
{
    __shared__ int sd[128];
    int t = threadIdx.x;
    int own = (t < nb) ? bsum[t] : 0;
    sd[t] = own;
    __syncthreads();
    #pragma unroll
    for (int off = 1; off < 128; off <<= 1) {
        int add = (t >= off) ? sd[t - off] : 0;
        __syncthreads();
        sd[t] += add;
        __syncthreads();
    }
    if (t < nb) bsum[t] = sd[t] - own;
}

__global__ __launch_bounds__(256) void scan3_kernel(
    const int* __restrict__ part, const int* __restrict__ bsum,
    const int* __restrict__ deg, int* __restrict__ indptr,
    float* __restrict__ inv_deg, int n)
{
    int i = blockIdx.x * 256 + threadIdx.x;
    if (i >= n) return;
    int val = part[i] + bsum[i >> 10];
    indptr[i + 1] = val;
    int d = deg[i];
    inv_deg[i] = (d > 0) ? 1.0f / (float)d : 0.0f;
    if (i == 0) indptr[0] = 0;
}

// invg from sorted-boundary gstart + identity-init of the BN affine (A=1, C=0)
__global__ __launch_bounds__(512) void invg_kernel(
    const int* __restrict__ gstart, float* __restrict__ invg,
    float* __restrict__ ac, int G)
{
    int g = threadIdx.x;
    if (g < G) {
        int c = gstart[g + 1] - gstart[g];
        invg[g] = (c > 0) ? 1.0f / (float)c : 0.0f;
    }
    if (g < 64) ac[g] = 1.0f;
    else if (g < 128) ac[g] = 0.0f;
}

__global__ __launch_bounds__(256) void csr_fill_kernel(
    const int2* __restrict__ pairs, const int* __restrict__ bktoff,
    const int* __restrict__ indptr, int* __restrict__ esrc, int N)
{
    __shared__ int cur[256];
    int j = blockIdx.x, t = threadIdx.x;
    int idx = j * 256 + t;
    cur[t] = (idx < N) ? indptr[idx] : 0;
    __syncthreads();
    int e0 = bktoff[j], e1 = bktoff[j + 1];
    for (int i = e0 + t; i < e1; i += 256) {
        int2 e = pairs[i];
        int p = atomicAdd(&cur[e.x & 255], 1);
        esrc[p] = e.y;
    }
}

// ---------- per-layer ----------
// agg (round 13): edge-index broadcast, explicit 16-deep gather batches.
// zout = A*(z_own + mean(z_nb)) + C*(1+[deg>0])
__global__ __launch_bounds__(256) void agg_kernel(
    const float* __restrict__ zprev, const ushort_t* __restrict__ zb,
    const int* __restrict__ indptr, const int* __restrict__ esrc,
    const float* __restrict__ inv_deg, const float* __restrict__ ac,
    float* __restrict__ zout, int n)
{
    int t = threadIdx.x;
    int grp = t >> 4, l = t & 15;
    int lane = t & 63;
    int gl0 = lane & 48;
    int node = blockIdx.x * 16 + grp;
    if (node >= n) return;
    int e0 = indptr[node], e1 = indptr[node + 1];
    // hoisted independent loads: overlap with the gather loop
    float idg = inv_deg[node];
    float4 own = *(const float4*)(zprev + (size_t)node * 64 + l * 4);
    float4 A = *(const float4*)(ac + l * 4);
    float4 C = *(const float4*)(ac + 64 + l * 4);
    float a0 = 0.f, a1 = 0.f, a2 = 0.f, a3 = 0.f;
    const ushort_t* zbl = zb + l * 4;

    int base = e0;
    // full chunks: 16 gathers batched (issue loop separate from accumulate)
    for (; base + 16 <= e1; base += 16) {
        int myi = esrc[base + l];
        uint2 vv[16];
        #pragma unroll
        for (int j = 0; j < 16; ++j) {
            int s = __shfl(myi, gl0 + j, 64);
            vv[j] = *(const uint2*)(zbl + (size_t)s * 64);
        }
        #pragma unroll
        for (int j = 0; j < 16; ++j) {
            a0 += __uint_as_float(vv[j].x << 16);
            a1 += __uint_as_float(vv[j].x & 0xffff0000u);
            a2 += __uint_as_float(vv[j].y << 16);
            a3 += __uint_as_float(vv[j].y & 0xffff0000u);
        }
    }
    // remainder: masked 16-wide batch; pad lanes re-read edge-0's row (L1 hit)
    // and are forced to +0.0f => accumulation chain is bit-identical.
    int cnt = e1 - base;
    if (cnt > 0) {
        int myi = (l < cnt) ? esrc[base + l] : 0;
        uint2 vv[16];
        #pragma unroll
        for (int j = 0; j < 16; ++j) {
            int jj = (j < cnt) ? j : 0;
            int s = __shfl(myi, gl0 + jj, 64);
            uint2 v = *(const uint2*)(zbl + (size_t)s * 64);
            vv[j].x = (j < cnt) ? v.x : 0u;
            vv[j].y = (j < cnt) ? v.y : 0u;
        }
        #pragma unroll
        for (int j = 0; j < 16; ++j) {
            a0 += __uint_as_float(vv[j].x << 16);
            a1 += __uint_as_float(vv[j].x & 0xffff0000u);
            a2 += __uint_as_float(vv[j].y << 16);
            a3 += __uint_as_float(vv[j].y & 0xffff0000u);
        }
    }

    float cf = (idg > 0.f) ? 2.f : 1.f;
    float4 r;
    r.x = fmaf(A.x, fmaf(idg, a0, own.x), C.x * cf);
    r.y = fmaf(A.y, fmaf(idg, a1, own.y), C.y * cf);
    r.z = fmaf(A.z, fmaf(idg, a2, own.z), C.z * cf);
    r.w = fmaf(A.w, fmaf(idg, a3, own.w), C.w * cf);
    *(float4*)(zout + (size_t)node * 64 + l * 4) = r;
}

// MLP: 4 lanes per node, each owns 16 features. Shared operands broadcast
// via __shfl within the 4-lane group; same k-order FMA chain as round 10.
__global__ __launch_bounds__(256, 2) void mlp_kernel(
    float* __restrict__ zf, ushort_t* __restrict__ zb,
    const float* __restrict__ W1f, const float* __restrict__ b1f,
    const float* __restrict__ W2f, const float* __restrict__ b2f,
    int n)
{
    __shared__ float w1s[4096];
    __shared__ float w2s[4096];
    __shared__ float bs[128];
    int t = threadIdx.x;
    for (int i = t; i < 4096; i += 256) {
        w1s[i] = W1f[i];
        w2s[i] = W2f[i];
    }
    if (t < 64) bs[t] = b1f[t];
    else if (t < 128) bs[t] = b2f[t - 64];
    __syncthreads();

    int idx = blockIdx.x * 256 + t;
    int node = idx >> 2;
    if (node >= n) return;
    int sub = t & 3;
    int lane = t & 63;
    int grp = lane & ~3;          // base lane of my 4-lane group
    int j0 = sub * 16;
    float* zrow = zf + (size_t)node * 64;
    ushort_t* zbrow = zb + (size_t)node * 64;

    // my quarter of z
    float zc[16];
    {
        const float4* zp = (const float4*)(zrow + j0);
        #pragma unroll
        for (int q = 0; q < 4; ++q) {
            float4 v = zp[q];
            zc[4*q] = v.x; zc[4*q+1] = v.y; zc[4*q+2] = v.z; zc[4*q+3] = v.w;
        }
    }

    // GEMM1: y[j0..j0+16)
    float y[16];
    #pragma unroll
    for (int q = 0; q < 16; ++q) y[q] = bs[j0 + q];
    #pragma unroll
    for (int k = 0; k < 64; ++k) {
        float a = __shfl(zc[k & 15], grp + (k >> 4), 64);
        const float4* w = (const float4*)(w1s + k * 64 + j0);
        #pragma unroll
        for (int q = 0; q < 4; ++q) {
            float4 wv = w[q];
            y[4*q]   = fmaf(a, wv.x, y[4*q]);
            y[4*q+1] = fmaf(a, wv.y, y[4*q+1]);
            y[4*q+2] = fmaf(a, wv.z, y[4*q+2]);
            y[4*q+3] = fmaf(a, wv.w, y[4*q+3]);
        }
    }
    #pragma unroll
    for (int q = 0; q < 16; ++q) y[q] = fmaxf(y[q], 0.f);

    // GEMM2: o[j0..j0+16)
    float o[16];
    #pragma unroll
    for (int q = 0; q < 16; ++q) o[q] = bs[64 + j0 + q];
    #pragma unroll
    for (int k = 0; k < 64; ++k) {
        float a = __shfl(y[k & 15], grp + (k >> 4), 64);
        const float4* w = (const float4*)(w2s + k * 64 + j0);
        #pragma unroll
        for (int q = 0; q < 4; ++q) {
            float4 wv = w[q];
            o[4*q]   = fmaf(a, wv.x, o[4*q]);
            o[4*q+1] = fmaf(a, wv.y, o[4*q+1]);
            o[4*q+2] = fmaf(a, wv.z, o[4*q+2]);
            o[4*q+3] = fmaf(a, wv.w, o[4*q+3]);
        }
    }

    // relu + store fp32 + bf16 mirror (group-contiguous)
    #pragma unroll
    for (int q = 0; q < 4; ++q) {
        float4 v;
        v.x = fmaxf(o[4*q],   0.f);
        v.y = fmaxf(o[4*q+1], 0.f);
        v.z = fmaxf(o[4*q+2], 0.f);
        v.w = fmaxf(o[4*q+3], 0.f);
        *(float4*)(zrow + j0 + q * 4) = v;
        __hip_bfloat16 p0 = __float2bfloat16(v.x);
        __hip_bfloat16 p1 = __float2bfloat16(v.y);
        __hip_bfloat16 p2 = __float2bfloat16(v.z);
        __hip_bfloat16 p3 = __float2bfloat16(v.w);
        uint2 pw;
        pw.x = (uint_t)*(ushort_t*)&p0 | ((uint_t)*(ushort_t*)&p1 << 16);
        pw.y = (uint_t)*(ushort_t*)&p2 | ((uint_t)*(ushort_t*)&p3 << 16);
        *(uint2*)(zbrow + j0 + q * 4) = pw;
    }
}

// per-feature sum / sumsq -> float atomics (128 addresses)
__global__ __launch_bounds__(256) void stats_kernel(
    const float* __restrict__ z, float* __restrict__ stats, int N)
{
    __shared__ float ssum[256], ssq[256];
    int t = threadIdx.x;
    float s = 0.f, q = 0.f;
    int total = N * 64;
    for (int i = blockIdx.x * 256 + t; i < total; i += 256 * gridDim.x) {
        float v = z[i];
        s += v;
        q += v * v;
    }
    ssum[t] = s; ssq[t] = q;
    __syncthreads();
    if (t < 64) {
        float S = ssum[t] + ssum[t+64] + ssum[t+128] + ssum[t+192];
        float Q = ssq[t]  + ssq[t+64]  + ssq[t+128]  + ssq[t+192];
        atomicAdd(&stats[t], S);
        atomicAdd(&stats[64 + t], Q);
    }
}

__global__ __launch_bounds__(64) void bnfin_kernel(
    const float* __restrict__ stats, const float* __restrict__ gammaf,
    const float* __restrict__ betaf, float* __restrict__ ac, int N)
{
    int f = threadIdx.x;
    if (f >= 64) return;
    float invN = 1.0f / (float)N;
    float mu = stats[f] * invN;
    float var = stats[64 + f] * invN - mu * mu;
    if (var < 0.f) var = 0.f;
    float inv = rsqrtf(var + 1e-5f);
    float A = gammaf[f] * inv;
    float C = betaf[f] - mu * A;
    ac[f] = A;
    ac[64 + f] = C;
}

// pools only: h = A*z + C on the fly; node_pool (+=), gpool run-length atomics
__global__ __launch_bounds__(256) void pool_kernel(
    const float* __restrict__ z, float* __restrict__ node_pool,
    const int* __restrict__ b32, const float* __restrict__ ac,
    float* __restrict__ gpool, int N, int first)
{
    int wave = (blockIdx.x * 256 + threadIdx.x) >> 6;
    int f = threadIdx.x & 63;
    int n0 = wave * 64;
    if (n0 >= N) return;
    int n1 = min(n0 + 64, N);
    float A = ac[f], C = ac[64 + f];
    float racc = 0.f;
    int cur = b32[n0];
    for (int n = n0; n < n1; ++n) {
        int g = b32[n];
        if (g != cur) {  // wave-uniform branch
            atomicAdd(&gpool[(size_t)cur * 64 + f], racc);
            racc = 0.f;
            cur = g;
        }
        size_t idx = (size_t)n * 64 + f;
        float hv = fmaf(z[idx], A, C);
        float np = first ? hv : (node_pool[idx] + hv);
        node_pool[idx] = np;
        racc += hv;
    }
    atomicAdd(&gpool[(size_t)cur * 64 + f], racc);
}

__global__ __launch_bounds__(256) void finalize_kernel(
    const float* __restrict__ node_pool, const float* __restrict__ gpool,
    const float* __restrict__ invg, const int* __restrict__ flags,
    void* __restrict__ out, int N)
{
    int i = blockIdx.x * 256 + threadIdx.x;
    int nd = N * 64;
    int total = nd + GG * 64;
    if (i >= total) return;
    float v;
    if (i < nd) v = node_pool[i];
    else { int j = i - nd; v = gpool[j] * invg[j >> 6]; }
    if (flags[0]) ((float*)out)[i] = v;
    else ((__hip_bfloat16*)out)[i] = __float2bfloat16(v);
}

extern "C" void kernel_launch(void* const* d_in, const int* in_sizes, int n_in,
                              void* d_out, int out_size, void* d_ws, size_t ws_size,
                              hipStream_t stream)
{
    constexpr int N = NN, E = EE, G = GG;
    constexpr int ND = N * 64;

    const void* x     = d_in[0];
    const void* W1    = d_in[1];
    const void* b1    = d_in[2];
    const void* W2    = d_in[3];
    const void* b2    = d_in[4];
    const void* gamma = d_in[5];
    const void* beta  = d_in[6];
    const int* ei     = (const int*)d_in[7];
    const int* batw   = (const int*)d_in[8];

    char* p = (char*)d_ws;
    auto alloc = [&](size_t bytes) -> char* {
        char* r = p;
        p += (bytes + 255) & ~(size_t)255;
        return r;
    };
    float*    zbufA     = (float*)alloc((size_t)ND * 4);
    float*    zbufB     = (float*)alloc((size_t)ND * 4);
    float*    node_pool = (float*)alloc((size_t)ND * 4);
    ushort_t* zb        = (ushort_t*)alloc((size_t)ND * 2);
    int*      esrc      = (int*)alloc((size_t)E * 4);
    int*      indptr    = (int*)alloc((size_t)(N + 1) * 4);
    int*      deg       = (int*)alloc((size_t)N * 4);
    int*      part      = (int*)alloc((size_t)N * 4);
    float*    invdeg    = (float*)alloc((size_t)N * 4);
    int*      b32       = (int*)alloc((size_t)N * 4);
    int*      bsum      = (int*)alloc(128 * 4);
    int*      gstart    = (int*)alloc((size_t)(G + 1) * 4);
    float*    invg      = (float*)alloc(G * 4);
    float*    gpool     = (float*)alloc((size_t)G * 64 * 4);
    float*    stats     = (float*)alloc(128 * 4);
    float*    ac        = (float*)alloc(128 * 4);
    float*    wf        = (float*)alloc(33792 * 4);
    int*      flags     = (int*)alloc(16 * 4);
    int*      histo     = (int*)alloc((size_t)NBK * NHB * 4);
    int*      tot       = (int*)alloc((size_t)NBK * 4);
    int*      bktoff    = (int*)alloc((size_t)(NBK + 1) * 4);
    // pairs aliases node_pool: dead until first pool_kernel; E*8 == ND*4 bytes
    int2*     pairs     = (int2*)node_pool;

    hipMemsetAsync(gpool, 0, (size_t)G * 64 * 4, stream);

    detect_kernel<<<1, 256, 0, stream>>>(
        (const uint_t*)x, (const uint_t*)ei, (const uint_t*)batw, flags);
    cvt_w_kernel<<<132, 256, 0, stream>>>(W1, b1, W2, b2, gamma, beta, flags, wf);
    cvt_x_kernel<<<(ND + 255) / 256, 256, 0, stream>>>(x, flags, zbufA, zb, ND);
    cvt_batch_kernel<<<(N + 255) / 256, 256, 0, stream>>>(batw, flags, b32, gstart, N);
    count_hist_kernel<<<NHB, 256, 0, stream>>>(ei, flags, histo, E);
    blockscan_kernel<<<NBK, NHB, 0, stream>>>(histo, tot);
    bscan_kernel<<<1, 512, 0, stream>>>(tot, bktoff);
    pair_scatter_kernel<<<NHB, 256, 0, stream>>>(ei, flags, histo, bktoff, pairs, E);
    bucket_deg_kernel<<<NBK, 256, 0, stream>>>(pairs, bktoff, deg, N);
    int nb = (N + 1023) / 1024;  // 98
    scan1_kernel<<<nb, 256, 0, stream>>>(deg, part, bsum, N);
    scan2_kernel<<<1, 128, 0, stream>>>(bsum, nb);
    scan3_kernel<<<(N + 255) / 256, 256, 0, stream>>>(part, bsum, deg, indptr, invdeg, N);
    invg_kernel<<<1, 512, 0, stream>>>(gstart, invg, ac, G);
    csr_fill_kernel<<<NBK, 256, 0, stream>>>(pairs, bktoff, indptr, esrc, N);

    float* zin = zbufA;
    float* zout = zbufB;
    for (int l = 0; l < 4; ++l) {
        agg_kernel<<<(N + 15) / 16, 256, 0, stream>>>(
            zin, zb, indptr, esrc, invdeg, ac, zout, N);
        mlp_kernel<<<(N * 4 + 255) / 256, 256, 0, stream>>>(
            zout, zb, wf + l * 4096, wf + 32768 + l * 64,
            wf + 16384 + l * 4096, wf + 33024 + l * 64, N);
        hipMemsetAsync(stats, 0, 128 * 4, stream);
        stats_kernel<<<256, 256, 0, stream>>>(zout, stats, N);
        bnfin_kernel<<<1, 64, 0, stream>>>(
            stats, wf + 33280 + l * 64, wf + 33536 + l * 64, ac, N);
        pool_kernel<<<(N + 255) / 256, 256, 0, stream>>>(
            zout, node_pool, b32, ac, gpool, N, (l == 0) ? 1 : 0);
        float* tmp = zin; zin = zout; zout = tmp;
    }
    finalize_kernel<<<(ND + G * 64 + 255) / 256, 256, 0, stream>>>(
        node_pool, gpool, invg, flags, d_out, N);
}

// Round 4
// 807.425 us; speedup vs baseline: 1.3366x; 1.2104x over previous
//
#include <hip/hip_runtime.h>
#include <hip/hip_bf16.h>

// GIN_34789235098229 — round 14b: resubmit of round 14 (infra failure, no verdict).
// Round 13 = 977.3 us; top-4 = pool_kernel @58.3us x4: VALU 2.5%, hbm 11%,
// Occupancy 13.7%, VGPR=12 => latency-bound serial walk of 64 nodes/wave with
// one iteration in flight. Fix: 16 nodes/wave (6250 waves, ~24/CU) and 4-node
// batches per iteration (int4 b32 load, 4 independent z loads + node_pool rmw,
// then per-node run-length gpool accumulation in original order). Also dropped
// the 4 in-loop stats memsets: invg_kernel zeroes stats once, bnfin_kernel
// re-zeroes after consuming. Everything else unchanged from round 13.

typedef unsigned short ushort_t;
typedef unsigned int uint_t;

#define NN 100000
#define EE 3200000
#define GG 512
#define NBK 391    // ceil(NN/256); bucket = node >> 8
#define NHB 256    // histogram blocks
#define ECHUNK 12500  // EE / NHB exactly

// ---------- detection ----------
__global__ __launch_bounds__(256) void detect_kernel(
    const uint_t* __restrict__ xw, const uint_t* __restrict__ ew,
    const uint_t* __restrict__ bw, int* __restrict__ flags)
{
    __shared__ int sb[256], se[256], sbb[256];
    int t = threadIdx.x;
    uint_t w = xw[t];
    uint_t eL = (w >> 7) & 0xffu;
    sb[t] = (eL >= 112u && eL <= 135u) ? 1 : 0;
    se[t] = (ew[2 * t + 1] == 0u) ? 1 : 0;
    sbb[t] = (bw[NN - 512 + 2 * t + 1] == 0u) ? 1 : 0;
    __syncthreads();
    for (int off = 128; off > 0; off >>= 1) {
        if (t < off) { sb[t] += sb[t + off]; se[t] += se[t + off]; sbb[t] += sbb[t + off]; }
        __syncthreads();
    }
    if (t == 0) {
        flags[0] = (sb[0] < 128) ? 1 : 0;   // 1 => fp32 floats
        flags[1] = (se[0] >= 128) ? 1 : 0;  // 1 => int64 edges
        flags[2] = (sbb[0] >= 128) ? 1 : 0; // 1 => int64 batch
    }
}

// ---------- canonicalization ----------
__global__ __launch_bounds__(256) void cvt_w_kernel(
    const void* __restrict__ W1, const void* __restrict__ b1,
    const void* __restrict__ W2, const void* __restrict__ b2,
    const void* __restrict__ g, const void* __restrict__ be,
    const int* __restrict__ flags, float* __restrict__ wf)
{
    int i = blockIdx.x * 256 + threadIdx.x;
    if (i >= 33792) return;
    const void* src; int off;
    if (i < 16384)      { src = W1; off = i; }
    else if (i < 32768) { src = W2; off = i - 16384; }
    else if (i < 33024) { src = b1; off = i - 32768; }
    else if (i < 33280) { src = b2; off = i - 33024; }
    else if (i < 33536) { src = g;  off = i - 33280; }
    else                { src = be; off = i - 33536; }
    float v = flags[0] ? ((const float*)src)[off]
                       : __bfloat162float(((const __hip_bfloat16*)src)[off]);
    wf[i] = v;
}

__global__ __launch_bounds__(256) void cvt_x_kernel(
    const void* __restrict__ x, const int* __restrict__ flags,
    float* __restrict__ zA, ushort_t* __restrict__ zb, int total)
{
    int i = blockIdx.x * 256 + threadIdx.x;
    if (i >= total) return;
    float v;
    ushort_t bits;
    if (flags[0]) {
        v = ((const float*)x)[i];
        __hip_bfloat16 b = __float2bfloat16(v);
        bits = *(ushort_t*)&b;
    } else {
        bits = ((const ushort_t*)x)[i];
        uint_t u = (uint_t)bits << 16;
        v = __uint_as_float(u);
    }
    zA[i] = v;
    zb[i] = bits;
}

// batch is SORTED: zero-atomic group offsets via boundary detection.
// gstart[g] (G+1 entries) = first index i with batch[i] >= g.
__global__ __launch_bounds__(256) void cvt_batch_kernel(
    const int* __restrict__ bw, const int* __restrict__ flags,
    int* __restrict__ b32, int* __restrict__ gstart, int n)
{
    int i = blockIdx.x * 256 + threadIdx.x;
    if (i >= n) return;
    int i64 = flags[2];
    int v = i64 ? bw[2 * i] : bw[i];
    b32[i] = v;
    int vn = (i + 1 < n) ? (i64 ? bw[2 * (i + 1)] : bw[i + 1]) : GG;
    if (i == 0) {
        for (int g = 0; g <= v; ++g) gstart[g] = 0;
    }
    if (vn != v) {
        for (int g = v + 1; g <= vn; ++g) gstart[g] = i + 1;
    }
}

// ---------- atomic-free CSR build (round 9, unchanged) ----------
__global__ __launch_bounds__(256) void count_hist_kernel(
    const int* __restrict__ ei, const int* __restrict__ flags,
    int* __restrict__ histo, int E)
{
    __shared__ int lh[NBK];
    int b = blockIdx.x, t = threadIdx.x;
    for (int j = t; j < NBK; j += 256) lh[j] = 0;
    __syncthreads();
    int i64 = flags[1];
    int e0 = b * ECHUNK, e1 = min(e0 + ECHUNK, E);
    for (int i = e0 + t; i < e1; i += 256) {
        int d = i64 ? ei[2 * (E + i)] : ei[E + i];
        atomicAdd(&lh[d >> 8], 1);
    }
    __syncthreads();
    for (int j = t; j < NBK; j += 256) histo[j * NHB + b] = lh[j];
}

__global__ __launch_bounds__(NHB) void blockscan_kernel(
    int* __restrict__ histo, int* __restrict__ tot)
{
    __shared__ int sd[NHB];
    int j = blockIdx.x, t = threadIdx.x;
    int v = histo[j * NHB + t];
    sd[t] = v;
    __syncthreads();
    #pragma unroll
    for (int off = 1; off < NHB; off <<= 1) {
        int add = (t >= off) ? sd[t - off] : 0;
        __syncthreads();
        sd[t] += add;
        __syncthreads();
    }
    histo[j * NHB + t] = sd[t] - v;
    if (t == NHB - 1) tot[j] = sd[NHB - 1];
}

__global__ __launch_bounds__(512) void bscan_kernel(
    const int* __restrict__ tot, int* __restrict__ bktoff)
{
    __shared__ int sd[512];
    int t = threadIdx.x;
    int v = (t < NBK) ? tot[t] : 0;
    sd[t] = v;
    __syncthreads();
    #pragma unroll
    for (int off = 1; off < 512; off <<= 1) {
        int add = (t >= off) ? sd[t - off] : 0;
        __syncthreads();
        sd[t] += add;
        __syncthreads();
    }
    if (t < NBK) bktoff[t] = sd[t] - v;
    if (t == 511) bktoff[NBK] = sd[511];
}

__global__ __launch_bounds__(256) void pair_scatter_kernel(
    const int* __restrict__ ei, const int* __restrict__ flags,
    const int* __restrict__ histo, const int* __restrict__ bktoff,
    int2* __restrict__ pairs, int E)
{
    __shared__ int cur[NBK];
    int b = blockIdx.x, t = threadIdx.x;
    for (int j = t; j < NBK; j += 256) cur[j] = histo[j * NHB + b] + bktoff[j];
    __syncthreads();
    int i64 = flags[1];
    int e0 = b * ECHUNK, e1 = min(e0 + ECHUNK, E);
    for (int i = e0 + t; i < e1; i += 256) {
        int d = i64 ? ei[2 * (E + i)] : ei[E + i];
        int s = i64 ? ei[2 * i]       : ei[i];
        int p = atomicAdd(&cur[d >> 8], 1);
        pairs[p] = make_int2(d, s);
    }
}

__global__ __launch_bounds__(256) void bucket_deg_kernel(
    const int2* __restrict__ pairs, const int* __restrict__ bktoff,
    int* __restrict__ deg, int N)
{
    __shared__ int cnt[256];
    int j = blockIdx.x, t = threadIdx.x;
    cnt[t] = 0;
    __syncthreads();
    int e0 = bktoff[j], e1 = bktoff[j + 1];
    for (int i = e0 + t; i < e1; i += 256)
        atomicAdd(&cnt[pairs[i].x & 255], 1);
    __syncthreads();
    int idx = j * 256 + t;
    if (idx < N) deg[idx] = cnt[t];
}

__global__ __launch_bounds__(256) void scan1_kernel(
    const int* __restrict__ deg, int* __restrict__ part, int* __restrict__ bsum, int n)
{
    __shared__ int sd[256];
    int t = threadIdx.x;
    int i0 = blockIdx.x * 1024 + t * 4;
    int v0 = 0, v1 = 0, v2 = 0, v3 = 0;
    if (i0 + 3 < n) {
        int4 v = *(const int4*)(deg + i0);
        v0 = v.x; v1 = v.y; v2 = v.z; v3 = v.w;
    } else if (i0 < n) {
        v0 = deg[i0];
        if (i0 + 1 < n) v1 = deg[i0 + 1];
        if (i0 + 2 < n) v2 = deg[i0 + 2];
    }
    int s = v0 + v1 + v2 + v3;
    sd[t] = s;
    __syncthreads();
    #pragma unroll
    for (int off = 1; off < 256; off <<= 1) {
        int add = (t >= off) ? sd[t - off] : 0;
        __syncthreads();
        sd[t] += add;
        __syncthreads();
    }
    int incl = sd[t];
    int e0 = incl - s;
    int p0 = e0 + v0, p1 = p0 + v1, p2 = p1 + v2, p3 = p2 + v3;
    if (i0 < n)     part[i0]     = p0;
    if (i0 + 1 < n) part[i0 + 1] = p1;
    if (i0 + 2 < n) part[i0 + 2] = p2;
    if (i0 + 3 < n) part[i0 + 3] = p3;
    if (t == 255) bsum[blockIdx.x] = incl;
}

__global__ __launch_bounds__(128) void scan2_kernel(int* __restrict__ bsum, int nb)
{
    __shared__ int sd[128];
    int t = threadIdx.x;
    int own = (t < nb) ? bsum[t] : 0;
    sd[t] = own;
    __syncthreads();
    #pragma unroll
    for (int off = 1; off < 128; off <<= 1) {
        int add = (t >= off) ? sd[t - off] : 0;
        __syncthreads();
        sd[t] += add;
        __syncthreads();
    }
    if (t < nb) bsum[t] = sd[t] - own;
}

__global__ __launch_bounds__(256) void scan3_kernel(
    const int* __restrict__ part, const int* __restrict__ bsum,
    const int* __restrict__ deg, int* __restrict__ indptr,
    float* __restrict__ inv_deg, int n)
{
    int i = blockIdx.x * 256 + threadIdx.x;
    if (i >= n) return;
    int val = part[i] + bsum[i >> 10];
    indptr[i + 1] = val;
    int d = deg[i];
    inv_deg[i] = (d > 0) ? 1.0f / (float)d : 0.0f;
    if (i == 0) indptr[0] = 0;
}

// invg from sorted-boundary gstart + identity-init of the BN affine (A=1, C=0)
// + one-time zero of the stats accumulator.
__global__ __launch_bounds__(512) void invg_kernel(
    const int* __restrict__ gstart, float* __restrict__ invg,
    float* __restrict__ ac, float* __restrict__ stats, int G)
{
    int g = threadIdx.x;
    if (g < G) {
        int c = gstart[g + 1] - gstart[g];
        invg[g] = (c > 0) ? 1.0f / (float)c : 0.0f;
    }
    if (g < 64) ac[g] = 1.0f;
    else if (g < 128) ac[g] = 0.0f;
    if (g < 128) stats[g] = 0.0f;
}

__global__ __launch_bounds__(256) void csr_fill_kernel(
    const int2* __restrict__ pairs, const int* __restrict__ bktoff,
    const int* __restrict__ indptr, int* __restrict__ esrc, int N)
{
    __shared__ int cur[256];
    int j = blockIdx.x, t = threadIdx.x;
    int idx = j * 256 + t;
    cur[t] = (idx < N) ? indptr[idx] : 0;
    __syncthreads();
    int e0 = bktoff[j], e1 = bktoff[j + 1];
    for (int i = e0 + t; i < e1; i += 256) {
        int2 e = pairs[i];
        int p = atomicAdd(&cur[e.x & 255], 1);
        esrc[p] = e.y;
    }
}

// ---------- per-layer ----------
// agg (round 13): edge-index broadcast, explicit 16-deep gather batches.
// zout = A*(z_own + mean(z_nb)) + C*(1+[deg>0])
__global__ __launch_bounds__(256) void agg_kernel(
    const float* __restrict__ zprev, const ushort_t* __restrict__ zb,
    const int* __restrict__ indptr, const int* __restrict__ esrc,
    const float* __restrict__ inv_deg, const float* __restrict__ ac,
    float* __restrict__ zout, int n)
{
    int t = threadIdx.x;
    int grp = t >> 4, l = t & 15;
    int lane = t & 63;
    int gl0 = lane & 48;
    int node = blockIdx.x * 16 + grp;
    if (node >= n) return;
    int e0 = indptr[node], e1 = indptr[node + 1];
    // hoisted independent loads: overlap with the gather loop
    float idg = inv_deg[node];
    float4 own = *(const float4*)(zprev + (size_t)node * 64 + l * 4);
    float4 A = *(const float4*)(ac + l * 4);
    float4 C = *(const float4*)(ac + 64 + l * 4);
    float a0 = 0.f, a1 = 0.f, a2 = 0.f, a3 = 0.f;
    const ushort_t* zbl = zb + l * 4;

    int base = e0;
    // full chunks: 16 gathers batched (issue loop separate from accumulate)
    for (; base + 16 <= e1; base += 16) {
        int myi = esrc[base + l];
        uint2 vv[16];
        #pragma unroll
        for (int j = 0; j < 16; ++j) {
            int s = __shfl(myi, gl0 + j, 64);
            vv[j] = *(const uint2*)(zbl + (size_t)s * 64);
        }
        #pragma unroll
        for (int j = 0; j < 16; ++j) {
            a0 += __uint_as_float(vv[j].x << 16);
            a1 += __uint_as_float(vv[j].x & 0xffff0000u);
            a2 += __uint_as_float(vv[j].y << 16);
            a3 += __uint_as_float(vv[j].y & 0xffff0000u);
        }
    }
    // remainder: masked 16-wide batch; pad lanes re-read edge-0's row (L1 hit)
    // and are forced to +0.0f => accumulation chain is bit-identical.
    int cnt = e1 - base;
    if (cnt > 0) {
        int myi = (l < cnt) ? esrc[base + l] : 0;
        uint2 vv[16];
        #pragma unroll
        for (int j = 0; j < 16; ++j) {
            int jj = (j < cnt) ? j : 0;
            int s = __shfl(myi, gl0 + jj, 64);
            uint2 v = *(const uint2*)(zbl + (size_t)s * 64);
            vv[j].x = (j < cnt) ? v.x : 0u;
            vv[j].y = (j < cnt) ? v.y : 0u;
        }
        #pragma unroll
        for (int j = 0; j < 16; ++j) {
            a0 += __uint_as_float(vv[j].x << 16);
            a1 += __uint_as_float(vv[j].x & 0xffff0000u);
            a2 += __uint_as_float(vv[j].y << 16);
            a3 += __uint_as_float(vv[j].y & 0xffff0000u);
        }
    }

    float cf = (idg > 0.f) ? 2.f : 1.f;
    float4 r;
    r.x = fmaf(A.x, fmaf(idg, a0, own.x), C.x * cf);
    r.y = fmaf(A.y, fmaf(idg, a1, own.y), C.y * cf);
    r.z = fmaf(A.z, fmaf(idg, a2, own.z), C.z * cf);
    r.w = fmaf(A.w, fmaf(idg, a3, own.w), C.w * cf);
    *(float4*)(zout + (size_t)node * 64 + l * 4) = r;
}

// MLP: 4 lanes per node, each owns 16 features. Shared operands broadcast
// via __shfl within the 4-lane group; same k-order FMA chain as round 10.
__global__ __launch_bounds__(256, 2) void mlp_kernel(
    float* __restrict__ zf, ushort_t* __restrict__ zb,
    const float* __restrict__ W1f, const float* __restrict__ b1f,
    const float* __restrict__ W2f, const float* __restrict__ b2f,
    int n)
{
    __shared__ float w1s[4096];
    __shared__ float w2s[4096];
    __shared__ float bs[128];
    int t = threadIdx.x;
    for (int i = t; i < 4096; i += 256) {
        w1s[i] = W1f[i];
        w2s[i] = W2f[i];
    }
    if (t < 64) bs[t] = b1f[t];
    else if (t < 128) bs[t] = b2f[t - 64];
    __syncthreads();

    int idx = blockIdx.x * 256 + t;
    int node = idx >> 2;
    if (node >= n) return;
    int sub = t & 3;
    int lane = t & 63;
    int grp = lane & ~3;          // base lane of my 4-lane group
    int j0 = sub * 16;
    float* zrow = zf + (size_t)node * 64;
    ushort_t* zbrow = zb + (size_t)node * 64;

    // my quarter of z
    float zc[16];
    {
        const float4* zp = (const float4*)(zrow + j0);
        #pragma unroll
        for (int q = 0; q < 4; ++q) {
            float4 v = zp[q];
            zc[4*q] = v.x; zc[4*q+1] = v.y; zc[4*q+2] = v.z; zc[4*q+3] = v.w;
        }
    }

    // GEMM1: y[j0..j0+16)
    float y[16];
    #pragma unroll
    for (int q = 0; q < 16; ++q) y[q] = bs[j0 + q];
    #pragma unroll
    for (int k = 0; k < 64; ++k) {
        float a = __shfl(zc[k & 15], grp + (k >> 4), 64);
        const float4* w = (const float4*)(w1s + k * 64 + j0);
        #pragma unroll
        for (int q = 0; q < 4; ++q) {
            float4 wv = w[q];
            y[4*q]   = fmaf(a, wv.x, y[4*q]);
            y[4*q+1] = fmaf(a, wv.y, y[4*q+1]);
            y[4*q+2] = fmaf(a, wv.z, y[4*q+2]);
            y[4*q+3] = fmaf(a, wv.w, y[4*q+3]);
        }
    }
    #pragma unroll
    for (int q = 0; q < 16; ++q) y[q] = fmaxf(y[q], 0.f);

    // GEMM2: o[j0..j0+16)
    float o[16];
    #pragma unroll
    for (int q = 0; q < 16; ++q) o[q] = bs[64 + j0 + q];
    #pragma unroll
    for (int k = 0; k < 64; ++k) {
        float a = __shfl(y[k & 15], grp + (k >> 4), 64);
        const float4* w = (const float4*)(w2s + k * 64 + j0);
        #pragma unroll
        for (int q = 0; q < 4; ++q) {
            float4 wv = w[q];
            o[4*q]   = fmaf(a, wv.x, o[4*q]);
            o[4*q+1] = fmaf(a, wv.y, o[4*q+1]);
            o[4*q+2] = fmaf(a, wv.z, o[4*q+2]);
            o[4*q+3] = fmaf(a, wv.w, o[4*q+3]);
        }
    }

    // relu + store fp32 + bf16 mirror (group-contiguous)
    #pragma unroll
    for (int q = 0; q < 4; ++q) {
        float4 v;
        v.x = fmaxf(o[4*q],   0.f);
        v.y = fmaxf(o[4*q+1], 0.f);
        v.z = fmaxf(o[4*q+2], 0.f);
        v.w = fmaxf(o[4*q+3], 0.f);
        *(float4*)(zrow + j0 + q * 4) = v;
        __hip_bfloat16 p0 = __float2bfloat16(v.x);
        __hip_bfloat16 p1 = __float2bfloat16(v.y);
        __hip_bfloat16 p2 = __float2bfloat16(v.z);
        __hip_bfloat16 p3 = __float2bfloat16(v.w);
        uint2 pw;
        pw.x = (uint_t)*(ushort_t*)&p0 | ((uint_t)*(ushort_t*)&p1 << 16);
        pw.y = (uint_t)*(ushort_t*)&p2 | ((uint_t)*(ushort_t*)&p3 << 16);
        *(uint2*)(zbrow + j0 + q * 4) = pw;
    }
}

// per-feature sum / sumsq -> float atomics (128 addresses)
__global__ __launch_bounds__(256) void stats_kernel(
    const float* __restrict__ z, float* __restrict__ stats, int N)
{
    __shared__ float ssum[256], ssq[256];
    int t = threadIdx.x;
    float s = 0.f, q = 0.f;
    int total = N * 64;
    for (int i = blockIdx.x * 256 + t; i < total; i += 256 * gridDim.x) {
        float v = z[i];
        s += v;
        q += v * v;
    }
    ssum[t] = s; ssq[t] = q;
    __syncthreads();
    if (t < 64) {
        float S = ssum[t] + ssum[t+64] + ssum[t+128] + ssum[t+192];
        float Q = ssq[t]  + ssq[t+64]  + ssq[t+128]  + ssq[t+192];
        atomicAdd(&stats[t], S);
        atomicAdd(&stats[64 + t], Q);
    }
}

// consumes stats -> (A,C), then re-zeroes stats for the next layer
__global__ __launch_bounds__(64) void bnfin_kernel(
    float* __restrict__ stats, const float* __restrict__ gammaf,
    const float* __restrict__ betaf, float* __restrict__ ac, int N)
{
    int f = threadIdx.x;
    if (f >= 64) return;
    float invN = 1.0f / (float)N;
    float mu = stats[f] * invN;
    float var = stats[64 + f] * invN - mu * mu;
    if (var < 0.f) var = 0.f;
    float inv = rsqrtf(var + 1e-5f);
    float A = gammaf[f] * inv;
    float C = betaf[f] - mu * A;
    ac[f] = A;
    ac[64 + f] = C;
    stats[f] = 0.0f;
    stats[64 + f] = 0.0f;
}

// pools only: h = A*z + C on the fly; node_pool (+=), gpool run-length atomics.
// Round 14: 16 nodes/wave, 4-node batches => 4x waves and 4x in-flight loads.
__global__ __launch_bounds__(256) void pool_kernel(
    const float* __restrict__ z, float* __restrict__ node_pool,
    const int* __restrict__ b32, const float* __restrict__ ac,
    float* __restrict__ gpool, int N, int first)
{
    int wave = (blockIdx.x * 256 + threadIdx.x) >> 6;
    int f = threadIdx.x & 63;
    int n0 = wave * 16;
    if (n0 >= N) return;
    int n1 = min(n0 + 16, N);
    float A = ac[f], C = ac[64 + f];
    float racc = 0.f;
    int cur = b32[n0];
    int n = n0;
    for (; n + 4 <= n1; n += 4) {
        int4 gv = *(const int4*)(b32 + n);
        size_t idx = (size_t)n * 64 + f;
        // 4 independent loads in flight
        float z0 = z[idx];
        float z1 = z[idx + 64];
        float z2 = z[idx + 128];
        float z3 = z[idx + 192];
        float h0 = fmaf(z0, A, C);
        float h1 = fmaf(z1, A, C);
        float h2 = fmaf(z2, A, C);
        float h3 = fmaf(z3, A, C);
        if (first) {
            node_pool[idx]       = h0;
            node_pool[idx + 64]  = h1;
            node_pool[idx + 128] = h2;
            node_pool[idx + 192] = h3;
        } else {
            float p0 = node_pool[idx];
            float p1 = node_pool[idx + 64];
            float p2 = node_pool[idx + 128];
            float p3 = node_pool[idx + 192];
            node_pool[idx]       = p0 + h0;
            node_pool[idx + 64]  = p1 + h1;
            node_pool[idx + 128] = p2 + h2;
            node_pool[idx + 192] = p3 + h3;
        }
        // run-length gpool accumulation, original per-node order
        int gs0 = gv.x, gs1 = gv.y, gs2 = gv.z, gs3 = gv.w;
        if (gs0 != cur) { atomicAdd(&gpool[(size_t)cur * 64 + f], racc); racc = 0.f; cur = gs0; }
        racc += h0;
        if (gs1 != cur) { atomicAdd(&gpool[(size_t)cur * 64 + f], racc); racc = 0.f; cur = gs1; }
        racc += h1;
        if (gs2 != cur) { atomicAdd(&gpool[(size_t)cur * 64 + f], racc); racc = 0.f; cur = gs2; }
        racc += h2;
        if (gs3 != cur) { atomicAdd(&gpool[(size_t)cur * 64 + f], racc); racc = 0.f; cur = gs3; }
        racc += h3;
    }
    for (; n < n1; ++n) {  // tail (unused when 16 | N; kept for safety)
        int g = b32[n];
        if (g != cur) { atomicAdd(&gpool[(size_t)cur * 64 + f], racc); racc = 0.f; cur = g; }
        size_t idx = (size_t)n * 64 + f;
        float hv = fmaf(z[idx], A, C);
        float np = first ? hv : (node_pool[idx] + hv);
        node_pool[idx] = np;
        racc += hv;
    }
    atomicAdd(&gpool[(size_t)cur * 64 + f], racc);
}

__global__ __launch_bounds__(256) void finalize_kernel(
    const float* __restrict__ node_pool, const float* __restrict__ gpool,
    const float* __restrict__ invg, const int* __restrict__ flags,
    void* __restrict__ out, int N)
{
    int i = blockIdx.x * 256 + threadIdx.x;
    int nd = N * 64;
    int total = nd + GG * 64;
    if (i >= total) return;
    float v;
    if (i < nd) v = node_pool[i];
    else { int j = i - nd; v = gpool[j] * invg[j >> 6]; }
    if (flags[0]) ((float*)out)[i] = v;
    else ((__hip_bfloat16*)out)[i] = __float2bfloat16(v);
}

extern "C" void kernel_launch(void* const* d_in, const int* in_sizes, int n_in,
                              void* d_out, int out_size, void* d_ws, size_t ws_size,
                              hipStream_t stream)
{
    constexpr int N = NN, E = EE, G = GG;
    constexpr int ND = N * 64;

    const void* x     = d_in[0];
    const void* W1    = d_in[1];
    const void* b1    = d_in[2];
    const void* W2    = d_in[3];
    const void* b2    = d_in[4];
    const void* gamma = d_in[5];
    const void* beta  = d_in[6];
    const int* ei     = (const int*)d_in[7];
    const int* batw   = (const int*)d_in[8];

    char* p = (char*)d_ws;
    auto alloc = [&](size_t bytes) -> char* {
        char* r = p;
        p += (bytes + 255) & ~(size_t)255;
        return r;
    };
    float*    zbufA     = (float*)alloc((size_t)ND * 4);
    float*    zbufB     = (float*)alloc((size_t)ND * 4);
    float*    node_pool = (float*)alloc((size_t)ND * 4);
    ushort_t* zb        = (ushort_t*)alloc((size_t)ND * 2);
    int*      esrc      = (int*)alloc((size_t)E * 4);
    int*      indptr    = (int*)alloc((size_t)(N + 1) * 4);
    int*      deg       = (int*)alloc((size_t)N * 4);
    int*      part      = (int*)alloc((size_t)N * 4);
    float*    invdeg    = (float*)alloc((size_t)N * 4);
    int*      b32       = (int*)alloc((size_t)N * 4);
    int*      bsum      = (int*)alloc(128 * 4);
    int*      gstart    = (int*)alloc((size_t)(G + 1) * 4);
    float*    invg      = (float*)alloc(G * 4);
    float*    gpool     = (float*)alloc((size_t)G * 64 * 4);
    float*    stats     = (float*)alloc(128 * 4);
    float*    ac        = (float*)alloc(128 * 4);
    float*    wf        = (float*)alloc(33792 * 4);
    int*      flags     = (int*)alloc(16 * 4);
    int*      histo     = (int*)alloc((size_t)NBK * NHB * 4);
    int*      tot       = (int*)alloc((size_t)NBK * 4);
    int*      bktoff    = (int*)alloc((size_t)(NBK + 1) * 4);
    // pairs aliases node_pool: dead until first pool_kernel; E*8 == ND*4 bytes
    int2*     pairs     = (int2*)node_pool;

    hipMemsetAsync(gpool, 0, (size_t)G * 64 * 4, stream);

    detect_kernel<<<1, 256, 0, stream>>>(
        (const uint_t*)x, (const uint_t*)ei, (const uint_t*)batw, flags);
    cvt_w_kernel<<<132, 256, 0, stream>>>(W1, b1, W2, b2, gamma, beta, flags, wf);
    cvt_x_kernel<<<(ND + 255) / 256, 256, 0, stream>>>(x, flags, zbufA, zb, ND);
    cvt_batch_kernel<<<(N + 255) / 256, 256, 0, stream>>>(batw, flags, b32, gstart, N);
    count_hist_kernel<<<NHB, 256, 0, stream>>>(ei, flags, histo, E);
    blockscan_kernel<<<NBK, NHB, 0, stream>>>(histo, tot);
    bscan_kernel<<<1, 512, 0, stream>>>(tot, bktoff);
    pair_scatter_kernel<<<NHB, 256, 0, stream>>>(ei, flags, histo, bktoff, pairs, E);
    bucket_deg_kernel<<<NBK, 256, 0, stream>>>(pairs, bktoff, deg, N);
    int nb = (N + 1023) / 1024;  // 98
    scan1_kernel<<<nb, 256, 0, stream>>>(deg, part, bsum, N);
    scan2_kernel<<<1, 128, 0, stream>>>(bsum, nb);
    scan3_kernel<<<(N + 255) / 256, 256, 0, stream>>>(part, bsum, deg, indptr, invdeg, N);
    invg_kernel<<<1, 512, 0, stream>>>(gstart, invg, ac, stats, G);
    csr_fill_kernel<<<NBK, 256, 0, stream>>>(pairs, bktoff, indptr, esrc, N);

    float* zin = zbufA;
    float* zout = zbufB;
    for (int l = 0; l < 4; ++l) {
        agg_kernel<<<(N + 15) / 16, 256, 0, stream>>>(
            zin, zb, indptr, esrc, invdeg, ac, zout, N);
        mlp_kernel<<<(N * 4 + 255) / 256, 256, 0, stream>>>(
            zout, zb, wf + l * 4096, wf + 32768 + l * 64,
            wf + 16384 + l * 4096, wf + 33024 + l * 64, N);
        stats_kernel<<<256, 256, 0, stream>>>(zout, stats, N);
        bnfin_kernel<<<1, 64, 0, stream>>>(
            stats, wf + 33280 + l * 64, wf + 33536 + l * 64, ac, N);
        pool_kernel<<<(N + 63) / 64, 256, 0, stream>>>(
            zout, node_pool, b32, ac, gpool, N, (l == 0) ? 1 : 0);
        float* tmp = zin; zin = zout; zout = tmp;
    }
    finalize_kernel<<<(ND + G * 64 + 255) / 256, 256, 0, stream>>>(
        node_pool, gpool, invg, flags, d_out, N);
}

// Round 5
// 802.408 us; speedup vs baseline: 1.3450x; 1.0063x over previous
//
#include <hip/hip_runtime.h>
#include <hip/hip_bf16.h>

// GIN_34789235098229 — round 15: fuse BN stats into mlp, inline bnfin into consumers.
// Round 14 = 807.4 us; top-5 all agg @55.8us (fetch 45%, VALU 44% — both pipes
// co-loaded, structural for the E x 128B gather). Cheapest structural win:
// per-layer stats_kernel re-reads the 25.6MB z that mlp just held in registers,
// and bnfin is a 1-block launch bubble. Fix: (a) mlp epilogue block-reduces
// h/h^2 (shfl_xor butterfly over lane strides 4..32 => per-wave, LDS combine
// 4 waves, 128 atomicAdd/block) into PER-LAYER stats buffers (zeroed once in
// invg; no re-zero hazard); invalid-node lanes contribute exact 0 (no early
// return => no divergent barrier). (b) agg/pool compute the BN affine (A,C)
// inline from stats+gamma+beta (identical formula to old bnfin, deterministic).
// Removes 8 dispatches + ~100MB traffic. Everything else unchanged.

typedef unsigned short ushort_t;
typedef unsigned int uint_t;

#define NN 100000
#define EE 3200000
#define GG 512
#define NBK 391    // ceil(NN/256); bucket = node >> 8
#define NHB 256    // histogram blocks
#define ECHUNK 12500  // EE / NHB exactly

// ---------- detection ----------
__global__ __launch_bounds__(256) void detect_kernel(
    const uint_t* __restrict__ xw, const uint_t* __restrict__ ew,
    const uint_t* __restrict__ bw, int* __restrict__ flags)
{
    __shared__ int sb[256], se[256], sbb[256];
    int t = threadIdx.x;
    uint_t w = xw[t];
    uint_t eL = (w >> 7) & 0xffu;
    sb[t] = (eL >= 112u && eL <= 135u) ? 1 : 0;
    se[t] = (ew[2 * t + 1] == 0u) ? 1 : 0;
    sbb[t] = (bw[NN - 512 + 2 * t + 1] == 0u) ? 1 : 0;
    __syncthreads();
    for (int off = 128; off > 0; off >>= 1) {
        if (t < off) { sb[t] += sb[t + off]; se[t] += se[t + off]; sbb[t] += sbb[t + off]; }
        __syncthreads();
    }
    if (t == 0) {
        flags[0] = (sb[0] < 128) ? 1 : 0;   // 1 => fp32 floats
        flags[1] = (se[0] >= 128) ? 1 : 0;  // 1 => int64 edges
        flags[2] = (sbb[0] >= 128) ? 1 : 0; // 1 => int64 batch
    }
}

// ---------- canonicalization ----------
__global__ __launch_bounds__(256) void cvt_w_kernel(
    const void* __restrict__ W1, const void* __restrict__ b1,
    const void* __restrict__ W2, const void* __restrict__ b2,
    const void* __restrict__ g, const void* __restrict__ be,
    const int* __restrict__ flags, float* __restrict__ wf)
{
    int i = blockIdx.x * 256 + threadIdx.x;
    if (i >= 33792) return;
    const void* src; int off;
    if (i < 16384)      { src = W1; off = i; }
    else if (i < 32768) { src = W2; off = i - 16384; }
    else if (i < 33024) { src = b1; off = i - 32768; }
    else if (i < 33280) { src = b2; off = i - 33024; }
    else if (i < 33536) { src = g;  off = i - 33280; }
    else                { src = be; off = i - 33536; }
    float v = flags[0] ? ((const float*)src)[off]
                       : __bfloat162float(((const __hip_bfloat16*)src)[off]);
    wf[i] = v;
}

__global__ __launch_bounds__(256) void cvt_x_kernel(
    const void* __restrict__ x, const int* __restrict__ flags,
    float* __restrict__ zA, ushort_t* __restrict__ zb, int total)
{
    int i = blockIdx.x * 256 + threadIdx.x;
    if (i >= total) return;
    float v;
    ushort_t bits;
    if (flags[0]) {
        v = ((const float*)x)[i];
        __hip_bfloat16 b = __float2bfloat16(v);
        bits = *(ushort_t*)&b;
    } else {
        bits = ((const ushort_t*)x)[i];
        uint_t u = (uint_t)bits << 16;
        v = __uint_as_float(u);
    }
    zA[i] = v;
    zb[i] = bits;
}

// batch is SORTED: zero-atomic group offsets via boundary detection.
// gstart[g] (G+1 entries) = first index i with batch[i] >= g.
__global__ __launch_bounds__(256) void cvt_batch_kernel(
    const int* __restrict__ bw, const int* __restrict__ flags,
    int* __restrict__ b32, int* __restrict__ gstart, int n)
{
    int i = blockIdx.x * 256 + threadIdx.x;
    if (i >= n) return;
    int i64 = flags[2];
    int v = i64 ? bw[2 * i] : bw[i];
    b32[i] = v;
    int vn = (i + 1 < n) ? (i64 ? bw[2 * (i + 1)] : bw[i + 1]) : GG;
    if (i == 0) {
        for (int g = 0; g <= v; ++g) gstart[g] = 0;
    }
    if (vn != v) {
        for (int g = v + 1; g <= vn; ++g) gstart[g] = i + 1;
    }
}

// ---------- atomic-free CSR build (round 9, unchanged) ----------
__global__ __launch_bounds__(256) void count_hist_kernel(
    const int* __restrict__ ei, const int* __restrict__ flags,
    int* __restrict__ histo, int E)
{
    __shared__ int lh[NBK];
    int b = blockIdx.x, t = threadIdx.x;
    for (int j = t; j < NBK; j += 256) lh[j] = 0;
    __syncthreads();
    int i64 = flags[1];
    int e0 = b * ECHUNK, e1 = min(e0 + ECHUNK, E);
    for (int i = e0 + t; i < e1; i += 256) {
        int d = i64 ? ei[2 * (E + i)] : ei[E + i];
        atomicAdd(&lh[d >> 8], 1);
    }
    __syncthreads();
    for (int j = t; j < NBK; j += 256) histo[j * NHB + b] = lh[j];
}

__global__ __launch_bounds__(NHB) void blockscan_kernel(
    int* __restrict__ histo, int* __restrict__ tot)
{
    __shared__ int sd[NHB];
    int j = blockIdx.x, t = threadIdx.x;
    int v = histo[j * NHB + t];
    sd[t] = v;
    __syncthreads();
    #pragma unroll
    for (int off = 1; off < NHB; off <<= 1) {
        int add = (t >= off) ? sd[t - off] : 0;
        __syncthreads();
        sd[t] += add;
        __syncthreads();
    }
    histo[j * NHB + t] = sd[t] - v;
    if (t == NHB - 1) tot[j] = sd[NHB - 1];
}

__global__ __launch_bounds__(512) void bscan_kernel(
    const int* __restrict__ tot, int* __restrict__ bktoff)
{
    __shared__ int sd[512];
    int t = threadIdx.x;
    int v = (t < NBK) ? tot[t] : 0;
    sd[t] = v;
    __syncthreads();
    #pragma unroll
    for (int off = 1; off < 512; off <<= 1) {
        int add = (t >= off) ? sd[t - off] : 0;
        __syncthreads();
        sd[t] += add;
        __syncthreads();
    }
    if (t < NBK) bktoff[t] = sd[t] - v;
    if (t == 511) bktoff[NBK] = sd[511];
}

__global__ __launch_bounds__(256) void pair_scatter_kernel(
    const int* __restrict__ ei, const int* __restrict__ flags,
    const int* __restrict__ histo, const int* __restrict__ bktoff,
    int2* __restrict__ pairs, int E)
{
    __shared__ int cur[NBK];
    int b = blockIdx.x, t = threadIdx.x;
    for (int j = t; j < NBK; j += 256) cur[j] = histo[j * NHB + b] + bktoff[j];
    __syncthreads();
    int i64 = flags[1];
    int e0 = b * ECHUNK, e1 = min(e0 + ECHUNK, E);
    for (int i = e0 + t; i < e1; i += 256) {
        int d = i64 ? ei[2 * (E + i)] : ei[E + i];
        int s = i64 ? ei[2 * i]       : ei[i];
        int p = atomicAdd(&cur[d >> 8], 1);
        pairs[p] = make_int2(d, s);
    }
}

__global__ __launch_bounds__(256) void bucket_deg_kernel(
    const int2* __restrict__ pairs, const int* __restrict__ bktoff,
    int* __restrict__ deg, int N)
{
    __shared__ int cnt[256];
    int j = blockIdx.x, t = threadIdx.x;
    cnt[t] = 0;
    __syncthreads();
    int e0 = bktoff[j], e1 = bktoff[j + 1];
    for (int i = e0 + t; i < e1; i += 256)
        atomicAdd(&cnt[pairs[i].x & 255], 1);
    __syncthreads();
    int idx = j * 256 + t;
    if (idx < N) deg[idx] = cnt[t];
}

__global__ __launch_bounds__(256) void scan1_kernel(
    const int* __restrict__ deg, int* __restrict__ part, int* __restrict__ bsum, int n)
{
    __shared__ int sd[256];
    int t = threadIdx.x;
    int i0 = blockIdx.x * 1024 + t * 4;
    int v0 = 0, v1 = 0, v2 = 0, v3 = 0;
    if (i0 + 3 < n) {
        int4 v = *(const int4*)(deg + i0);
        v0 = v.x; v1 = v.y; v2 = v.z; v3 = v.w;
    } else if (i0 < n) {
        v0 = deg[i0];
        if (i0 + 1 < n) v1 = deg[i0 + 1];
        if (i0 + 2 < n) v2 = deg[i0 + 2];
    }
    int s = v0 + v1 + v2 + v3;
    sd[t] = s;
    __syncthreads();
    #pragma unroll
    for (int off = 1; off < 256; off <<= 1) {
        int add = (t >= off) ? sd[t - off] : 0;
        __syncthreads();
        sd[t] += add;
        __syncthreads();
    }
    int incl = sd[t];
    int e0 = incl - s;
    int p0 = e0 + v0, p1 = p0 + v1, p2 = p1 + v2, p3 = p2 + v3;
    if (i0 < n)     part[i0]     = p0;
    if (i0 + 1 < n) part[i0 + 1] = p1;
    if (i0 + 2 < n) part[i0 + 2] = p2;
    if (i0 + 3 < n) part[i0 + 3] = p3;
    if (t == 255) bsum[blockIdx.x] = incl;
}

__global__ __launch_bounds__(128) void scan2_kernel(int* __restrict__ bsum, int nb)
{
    __shared__ int sd[128];
    int t = threadIdx.x;
    int own = (t < nb) ? bsum[t] : 0;
    sd[t] = own;
    __syncthreads();
    #pragma unroll
    for (int off = 1; off < 128; off <<= 1) {
        int add = (t >= off) ? sd[t - off] : 0;
        __syncthreads();
        sd[t] += add;
        __syncthreads();
    }
    if (t < nb) bsum[t] = sd[t] - own;
}

__global__ __launch_bounds__(256) void scan3_kernel(
    const int* __restrict__ part, const int* __restrict__ bsum,
    const int* __restrict__ deg, int* __restrict__ indptr,
    float* __restrict__ inv_deg, int n)
{
    int i = blockIdx.x * 256 + threadIdx.x;
    if (i >= n) return;
    int val = part[i] + bsum[i >> 10];
    indptr[i + 1] = val;
    int d = deg[i];
    inv_deg[i] = (d > 0) ? 1.0f / (float)d : 0.0f;
    if (i == 0) indptr[0] = 0;
}

// invg from sorted-boundary gstart + one-time zero of the 4 per-layer stats bufs
__global__ __launch_bounds__(512) void invg_kernel(
    const int* __restrict__ gstart, float* __restrict__ invg,
    float* __restrict__ stats4, int G)
{
    int g = threadIdx.x;
    if (g < G) {
        int c = gstart[g + 1] - gstart[g];
        invg[g] = (c > 0) ? 1.0f / (float)c : 0.0f;
    }
    if (g < 512) stats4[g] = 0.0f;
}

__global__ __launch_bounds__(256) void csr_fill_kernel(
    const int2* __restrict__ pairs, const int* __restrict__ bktoff,
    const int* __restrict__ indptr, int* __restrict__ esrc, int N)
{
    __shared__ int cur[256];
    int j = blockIdx.x, t = threadIdx.x;
    int idx = j * 256 + t;
    cur[t] = (idx < N) ? indptr[idx] : 0;
    __syncthreads();
    int e0 = bktoff[j], e1 = bktoff[j + 1];
    for (int i = e0 + t; i < e1; i += 256) {
        int2 e = pairs[i];
        int p = atomicAdd(&cur[e.x & 255], 1);
        esrc[p] = e.y;
    }
}

// ---------- per-layer ----------
// agg: edge-index broadcast, explicit 16-deep gather batches.
// BN affine (A,C) computed inline from prev layer's stats (use_bn) or identity.
// zout = A*(z_own + mean(z_nb)) + C*(1+[deg>0])
__global__ __launch_bounds__(256) void agg_kernel(
    const float* __restrict__ zprev, const ushort_t* __restrict__ zb,
    const int* __restrict__ indptr, const int* __restrict__ esrc,
    const float* __restrict__ inv_deg, const float* __restrict__ stats_l,
    const float* __restrict__ gammaf, const float* __restrict__ betaf,
    int use_bn, float* __restrict__ zout, int n)
{
    int t = threadIdx.x;
    int grp = t >> 4, l = t & 15;
    int lane = t & 63;
    int gl0 = lane & 48;
    int node = blockIdx.x * 16 + grp;
    if (node >= n) return;
    int e0 = indptr[node], e1 = indptr[node + 1];
    // hoisted independent loads: overlap with the gather loop
    float idg = inv_deg[node];
    float4 own = *(const float4*)(zprev + (size_t)node * 64 + l * 4);
    // inline BN affine of the PREVIOUS layer (identical formula to old bnfin)
    float4 A, C;
    if (use_bn) {
        const float invN = 1.0f / (float)NN;
        float4 s4 = *(const float4*)(stats_l + l * 4);
        float4 q4 = *(const float4*)(stats_l + 64 + l * 4);
        float4 g4 = *(const float4*)(gammaf + l * 4);
        float4 b4 = *(const float4*)(betaf + l * 4);
        float mu, var;
        mu = s4.x * invN; var = q4.x * invN - mu * mu; if (var < 0.f) var = 0.f;
        A.x = g4.x * rsqrtf(var + 1e-5f); C.x = b4.x - mu * A.x;
        mu = s4.y * invN; var = q4.y * invN - mu * mu; if (var < 0.f) var = 0.f;
        A.y = g4.y * rsqrtf(var + 1e-5f); C.y = b4.y - mu * A.y;
        mu = s4.z * invN; var = q4.z * invN - mu * mu; if (var < 0.f) var = 0.f;
        A.z = g4.z * rsqrtf(var + 1e-5f); C.z = b4.z - mu * A.z;
        mu = s4.w * invN; var = q4.w * invN - mu * mu; if (var < 0.f) var = 0.f;
        A.w = g4.w * rsqrtf(var + 1e-5f); C.w = b4.w - mu * A.w;
    } else {
        A = make_float4(1.f, 1.f, 1.f, 1.f);
        C = make_float4(0.f, 0.f, 0.f, 0.f);
    }
    float a0 = 0.f, a1 = 0.f, a2 = 0.f, a3 = 0.f;
    const ushort_t* zbl = zb + l * 4;

    int base = e0;
    // full chunks: 16 gathers batched (issue loop separate from accumulate)
    for (; base + 16 <= e1; base += 16) {
        int myi = esrc[base + l];
        uint2 vv[16];
        #pragma unroll
        for (int j = 0; j < 16; ++j) {
            int s = __shfl(myi, gl0 + j, 64);
            vv[j] = *(const uint2*)(zbl + (size_t)s * 64);
        }
        #pragma unroll
        for (int j = 0; j < 16; ++j) {
            a0 += __uint_as_float(vv[j].x << 16);
            a1 += __uint_as_float(vv[j].x & 0xffff0000u);
            a2 += __uint_as_float(vv[j].y << 16);
            a3 += __uint_as_float(vv[j].y & 0xffff0000u);
        }
    }
    // remainder: masked 16-wide batch; pad lanes re-read edge-0's row (L1 hit)
    // and are forced to +0.0f => accumulation chain is bit-identical.
    int cnt = e1 - base;
    if (cnt > 0) {
        int myi = (l < cnt) ? esrc[base + l] : 0;
        uint2 vv[16];
        #pragma unroll
        for (int j = 0; j < 16; ++j) {
            int jj = (j < cnt) ? j : 0;
            int s = __shfl(myi, gl0 + jj, 64);
            uint2 v = *(const uint2*)(zbl + (size_t)s * 64);
            vv[j].x = (j < cnt) ? v.x : 0u;
            vv[j].y = (j < cnt) ? v.y : 0u;
        }
        #pragma unroll
        for (int j = 0; j < 16; ++j) {
            a0 += __uint_as_float(vv[j].x << 16);
            a1 += __uint_as_float(vv[j].x & 0xffff0000u);
            a2 += __uint_as_float(vv[j].y << 16);
            a3 += __uint_as_float(vv[j].y & 0xffff0000u);
        }
    }

    float cf = (idg > 0.f) ? 2.f : 1.f;
    float4 r;
    r.x = fmaf(A.x, fmaf(idg, a0, own.x), C.x * cf);
    r.y = fmaf(A.y, fmaf(idg, a1, own.y), C.y * cf);
    r.z = fmaf(A.z, fmaf(idg, a2, own.z), C.z * cf);
    r.w = fmaf(A.w, fmaf(idg, a3, own.w), C.w * cf);
    *(float4*)(zout + (size_t)node * 64 + l * 4) = r;
}

// MLP: 4 lanes per node, each owns 16 features. Shared operands broadcast
// via __shfl within the 4-lane group; same k-order FMA chain as round 10.
// Round 15: epilogue block-reduces h / h^2 into per-layer stats (fused BN stats).
__global__ __launch_bounds__(256, 2) void mlp_kernel(
    float* __restrict__ zf, ushort_t* __restrict__ zb,
    const float* __restrict__ W1f, const float* __restrict__ b1f,
    const float* __restrict__ W2f, const float* __restrict__ b2f,
    float* __restrict__ stats_l, int n)
{
    __shared__ float w1s[4096];
    __shared__ float w2s[4096];
    __shared__ float bs[128];
    __shared__ float sred[256];
    __shared__ float qred[256];
    int t = threadIdx.x;
    for (int i = t; i < 4096; i += 256) {
        w1s[i] = W1f[i];
        w2s[i] = W2f[i];
    }
    if (t < 64) bs[t] = b1f[t];
    else if (t < 128) bs[t] = b2f[t - 64];
    __syncthreads();

    int idx = blockIdx.x * 256 + t;
    int node = idx >> 2;
    bool valid = node < n;          // no early return: all threads reach barriers
    int sub = t & 3;
    int lane = t & 63;
    int grp = lane & ~3;          // base lane of my 4-lane group
    int j0 = sub * 16;
    float* zrow = zf + (size_t)node * 64;
    ushort_t* zbrow = zb + (size_t)node * 64;

    // my quarter of z
    float zc[16];
    if (valid) {
        const float4* zp = (const float4*)(zrow + j0);
        #pragma unroll
        for (int q = 0; q < 4; ++q) {
            float4 v = zp[q];
            zc[4*q] = v.x; zc[4*q+1] = v.y; zc[4*q+2] = v.z; zc[4*q+3] = v.w;
        }
    } else {
        #pragma unroll
        for (int q = 0; q < 16; ++q) zc[q] = 0.f;
    }

    // GEMM1: y[j0..j0+16)
    float y[16];
    #pragma unroll
    for (int q = 0; q < 16; ++q) y[q] = bs[j0 + q];
    #pragma unroll
    for (int k = 0; k < 64; ++k) {
        float a = __shfl(zc[k & 15], grp + (k >> 4), 64);
        const float4* w = (const float4*)(w1s + k * 64 + j0);
        #pragma unroll
        for (int q = 0; q < 4; ++q) {
            float4 wv = w[q];
            y[4*q]   = fmaf(a, wv.x, y[4*q]);
            y[4*q+1] = fmaf(a, wv.y, y[4*q+1]);
            y[4*q+2] = fmaf(a, wv.z, y[4*q+2]);
            y[4*q+3] = fmaf(a, wv.w, y[4*q+3]);
        }
    }
    #pragma unroll
    for (int q = 0; q < 16; ++q) y[q] = fmaxf(y[q], 0.f);

    // GEMM2: o[j0..j0+16)
    float o[16];
    #pragma unroll
    for (int q = 0; q < 16; ++q) o[q] = bs[64 + j0 + q];
    #pragma unroll
    for (int k = 0; k < 64; ++k) {
        float a = __shfl(y[k & 15], grp + (k >> 4), 64);
        const float4* w = (const float4*)(w2s + k * 64 + j0);
        #pragma unroll
        for (int q = 0; q < 4; ++q) {
            float4 wv = w[q];
            o[4*q]   = fmaf(a, wv.x, o[4*q]);
            o[4*q+1] = fmaf(a, wv.y, o[4*q+1]);
            o[4*q+2] = fmaf(a, wv.z, o[4*q+2]);
            o[4*q+3] = fmaf(a, wv.w, o[4*q+3]);
        }
    }

    // outer relu
    float h[16];
    #pragma unroll
    for (int q = 0; q < 16; ++q) h[q] = fmaxf(o[q], 0.f);

    // store fp32 + bf16 mirror (group-contiguous)
    if (valid) {
        #pragma unroll
        for (int q = 0; q < 4; ++q) {
            float4 v;
            v.x = h[4*q]; v.y = h[4*q+1]; v.z = h[4*q+2]; v.w = h[4*q+3];
            *(float4*)(zrow + j0 + q * 4) = v;
            __hip_bfloat16 p0 = __float2bfloat16(v.x);
            __hip_bfloat16 p1 = __float2bfloat16(v.y);
            __hip_bfloat16 p2 = __float2bfloat16(v.z);
            __hip_bfloat16 p3 = __float2bfloat16(v.w);
            uint2 pw;
            pw.x = (uint_t)*(ushort_t*)&p0 | ((uint_t)*(ushort_t*)&p1 << 16);
            pw.y = (uint_t)*(ushort_t*)&p2 | ((uint_t)*(ushort_t*)&p3 << 16);
            *(uint2*)(zbrow + j0 + q * 4) = pw;
        }
    }

    // ---- fused BN stats: block-reduce h, h^2 -> 128 atomics into stats_l ----
    float qs[16];
    #pragma unroll
    for (int q = 0; q < 16; ++q) {
        float hv = valid ? h[q] : 0.f;
        h[q] = hv;
        qs[q] = hv * hv;
    }
    // butterfly over the 16 lanes sharing sub (lane strides 4,8,16,32)
    #pragma unroll
    for (int m = 4; m <= 32; m <<= 1) {
        #pragma unroll
        for (int q = 0; q < 16; ++q) {
            h[q]  += __shfl_xor(h[q],  m, 64);
            qs[q] += __shfl_xor(qs[q], m, 64);
        }
    }
    int w = t >> 6;
    if ((lane >> 2) == 0) {       // lanes 0..3: one representative per sub
        #pragma unroll
        for (int q = 0; q < 16; ++q) {
            sred[w * 64 + j0 + q] = h[q];
            qred[w * 64 + j0 + q] = qs[q];
        }
    }
    __syncthreads();
    if (t < 128) {
        int kind = t >> 6, f = t & 63;
        const float* src = kind ? qred : sred;
        float val = src[f] + src[64 + f] + src[128 + f] + src[192 + f];
        atomicAdd(&stats_l[kind * 64 + f], val);
    }
}

// pools only: BN affine inline from stats_l; node_pool (+=), gpool run-length.
__global__ __launch_bounds__(256) void pool_kernel(
    const float* __restrict__ z, float* __restrict__ node_pool,
    const int* __restrict__ b32, const float* __restrict__ stats_l,
    const float* __restrict__ gammaf, const float* __restrict__ betaf,
    float* __restrict__ gpool, int N, int first)
{
    int wave = (blockIdx.x * 256 + threadIdx.x) >> 6;
    int f = threadIdx.x & 63;
    int n0 = wave * 16;
    if (n0 >= N) return;
    int n1 = min(n0 + 16, N);
    // inline BN affine (identical formula to old bnfin)
    float A, C;
    {
        const float invN = 1.0f / (float)NN;
        float mu = stats_l[f] * invN;
        float var = stats_l[64 + f] * invN - mu * mu;
        if (var < 0.f) var = 0.f;
        A = gammaf[f] * rsqrtf(var + 1e-5f);
        C = betaf[f] - mu * A;
    }
    float racc = 0.f;
    int cur = b32[n0];
    int n = n0;
    for (; n + 4 <= n1; n += 4) {
        int4 gv = *(const int4*)(b32 + n);
        size_t idx = (size_t)n * 64 + f;
        // 4 independent loads in flight
        float z0 = z[idx];
        float z1 = z[idx + 64];
        float z2 = z[idx + 128];
        float z3 = z[idx + 192];
        float h0 = fmaf(z0, A, C);
        float h1 = fmaf(z1, A, C);
        float h2 = fmaf(z2, A, C);
        float h3 = fmaf(z3, A, C);
        if (first) {
            node_pool[idx]       = h0;
            node_pool[idx + 64]  = h1;
            node_pool[idx + 128] = h2;
            node_pool[idx + 192] = h3;
        } else {
            float p0 = node_pool[idx];
            float p1 = node_pool[idx + 64];
            float p2 = node_pool[idx + 128];
            float p3 = node_pool[idx + 192];
            node_pool[idx]       = p0 + h0;
            node_pool[idx + 64]  = p1 + h1;
            node_pool[idx + 128] = p2 + h2;
            node_pool[idx + 192] = p3 + h3;
        }
        // run-length gpool accumulation, original per-node order
        int gs0 = gv.x, gs1 = gv.y, gs2 = gv.z, gs3 = gv.w;
        if (gs0 != cur) { atomicAdd(&gpool[(size_t)cur * 64 + f], racc); racc = 0.f; cur = gs0; }
        racc += h0;
        if (gs1 != cur) { atomicAdd(&gpool[(size_t)cur * 64 + f], racc); racc = 0.f; cur = gs1; }
        racc += h1;
        if (gs2 != cur) { atomicAdd(&gpool[(size_t)cur * 64 + f], racc); racc = 0.f; cur = gs2; }
        racc += h2;
        if (gs3 != cur) { atomicAdd(&gpool[(size_t)cur * 64 + f], racc); racc = 0.f; cur = gs3; }
        racc += h3;
    }
    for (; n < n1; ++n) {  // tail (unused when 16 | N; kept for safety)
        int g = b32[n];
        if (g != cur) { atomicAdd(&gpool[(size_t)cur * 64 + f], racc); racc = 0.f; cur = g; }
        size_t idx = (size_t)n * 64 + f;
        float hv = fmaf(z[idx], A, C);
        float np = first ? hv : (node_pool[idx] + hv);
        node_pool[idx] = np;
        racc += hv;
    }
    atomicAdd(&gpool[(size_t)cur * 64 + f], racc);
}

__global__ __launch_bounds__(256) void finalize_kernel(
    const float* __restrict__ node_pool, const float* __restrict__ gpool,
    const float* __restrict__ invg, const int* __restrict__ flags,
    void* __restrict__ out, int N)
{
    int i = blockIdx.x * 256 + threadIdx.x;
    int nd = N * 64;
    int total = nd + GG * 64;
    if (i >= total) return;
    float v;
    if (i < nd) v = node_pool[i];
    else { int j = i - nd; v = gpool[j] * invg[j >> 6]; }
    if (flags[0]) ((float*)out)[i] = v;
    else ((__hip_bfloat16*)out)[i] = __float2bfloat16(v);
}

extern "C" void kernel_launch(void* const* d_in, const int* in_sizes, int n_in,
                              void* d_out, int out_size, void* d_ws, size_t ws_size,
                              hipStream_t stream)
{
    constexpr int N = NN, E = EE, G = GG;
    constexpr int ND = N * 64;

    const void* x     = d_in[0];
    const void* W1    = d_in[1];
    const void* b1    = d_in[2];
    const void* W2    = d_in[3];
    const void* b2    = d_in[4];
    const void* gamma = d_in[5];
    const void* beta  = d_in[6];
    const int* ei     = (const int*)d_in[7];
    const int* batw   = (const int*)d_in[8];

    char* p = (char*)d_ws;
    auto alloc = [&](size_t bytes) -> char* {
        char* r = p;
        p += (bytes + 255) & ~(size_t)255;
        return r;
    };
    float*    zbufA     = (float*)alloc((size_t)ND * 4);
    float*    zbufB     = (float*)alloc((size_t)ND * 4);
    float*    node_pool = (float*)alloc((size_t)ND * 4);
    ushort_t* zb        = (ushort_t*)alloc((size_t)ND * 2);
    int*      esrc      = (int*)alloc((size_t)E * 4);
    int*      indptr    = (int*)alloc((size_t)(N + 1) * 4);
    int*      deg       = (int*)alloc((size_t)N * 4);
    int*      part      = (int*)alloc((size_t)N * 4);
    float*    invdeg    = (float*)alloc((size_t)N * 4);
    int*      b32       = (int*)alloc((size_t)N * 4);
    int*      bsum      = (int*)alloc(128 * 4);
    int*      gstart    = (int*)alloc((size_t)(G + 1) * 4);
    float*    invg      = (float*)alloc(G * 4);
    float*    gpool     = (float*)alloc((size_t)G * 64 * 4);
    float*    stats4    = (float*)alloc(512 * 4);   // 4 layers x 128
    float*    wf        = (float*)alloc(33792 * 4);
    int*      flags     = (int*)alloc(16 * 4);
    int*      histo     = (int*)alloc((size_t)NBK * NHB * 4);
    int*      tot       = (int*)alloc((size_t)NBK * 4);
    int*      bktoff    = (int*)alloc((size_t)(NBK + 1) * 4);
    // pairs aliases node_pool: dead until first pool_kernel; E*8 == ND*4 bytes
    int2*     pairs     = (int2*)node_pool;

    hipMemsetAsync(gpool, 0, (size_t)G * 64 * 4, stream);

    detect_kernel<<<1, 256, 0, stream>>>(
        (const uint_t*)x, (const uint_t*)ei, (const uint_t*)batw, flags);
    cvt_w_kernel<<<132, 256, 0, stream>>>(W1, b1, W2, b2, gamma, beta, flags, wf);
    cvt_x_kernel<<<(ND + 255) / 256, 256, 0, stream>>>(x, flags, zbufA, zb, ND);
    cvt_batch_kernel<<<(N + 255) / 256, 256, 0, stream>>>(batw, flags, b32, gstart, N);
    count_hist_kernel<<<NHB, 256, 0, stream>>>(ei, flags, histo, E);
    blockscan_kernel<<<NBK, NHB, 0, stream>>>(histo, tot);
    bscan_kernel<<<1, 512, 0, stream>>>(tot, bktoff);
    pair_scatter_kernel<<<NHB, 256, 0, stream>>>(ei, flags, histo, bktoff, pairs, E);
    bucket_deg_kernel<<<NBK, 256, 0, stream>>>(pairs, bktoff, deg, N);
    int nb = (N + 1023) / 1024;  // 98
    scan1_kernel<<<nb, 256, 0, stream>>>(deg, part, bsum, N);
    scan2_kernel<<<1, 128, 0, stream>>>(bsum, nb);
    scan3_kernel<<<(N + 255) / 256, 256, 0, stream>>>(part, bsum, deg, indptr, invdeg, N);
    invg_kernel<<<1, 512, 0, stream>>>(gstart, invg, stats4, G);
    csr_fill_kernel<<<NBK, 256, 0, stream>>>(pairs, bktoff, indptr, esrc, N);

    float* zin = zbufA;
    float* zout = zbufB;
    for (int l = 0; l < 4; ++l) {
        int lp = (l == 0) ? 0 : (l - 1);
        agg_kernel<<<(N + 15) / 16, 256, 0, stream>>>(
            zin, zb, indptr, esrc, invdeg,
            stats4 + lp * 128, wf + 33280 + lp * 64, wf + 33536 + lp * 64,
            (l == 0) ? 0 : 1, zout, N);
        mlp_kernel<<<(N * 4 + 255) / 256, 256, 0, stream>>>(
            zout, zb, wf + l * 4096, wf + 32768 + l * 64,
            wf + 16384 + l * 4096, wf + 33024 + l * 64,
            stats4 + l * 128, N);
        pool_kernel<<<(N + 63) / 64, 256, 0, stream>>>(
            zout, node_pool, b32,
            stats4 + l * 128, wf + 33280 + l * 64, wf + 33536 + l * 64,
            gpool, N, (l == 0) ? 1 : 0);
        float* tmp = zin; zin = zout; zout = tmp;
    }
    finalize_kernel<<<(ND + G * 64 + 255) / 256, 256, 0, stream>>>(
        node_pool, gpool, invg, flags, d_out, N);
}

// Round 6
// 775.141 us; speedup vs baseline: 1.3923x; 1.0352x over previous
//
#include <hip/hip_runtime.h>
#include <hip/hip_bf16.h>

// GIN_34789235098229 — round 16: de-atomic the fused BN stats.
// Round 15 = 802 us; mlp regressed ~50->82.9us (occ 15.8%, VALU 28%, hbm 8%):
// the fused stats ended with 1563 blocks x 128 global atomicAdds into 128
// addresses => 1563 serialized L2 RMWs per address (~40us drain tail with most
// waves retired — matches the LOW avg occupancy). Fix: keep the butterfly
// (cheap) but store per-WAVE partials to partials[128][6252] (feature-major,
// plain stores, no barrier, no LDS) and reduce in a new redstats_kernel
// (64 blocks, 3.2MB coalesced L2-hot, ~3us) which directly emits the BN
// affine (A,C) into per-layer ac slots. agg/pool revert to round-14 ac loads
// (slot0 = identity from invg; slot l+1 = BN_l written by redstats_l).
// Everything else unchanged from round 15.

typedef unsigned short ushort_t;
typedef unsigned int uint_t;

#define NN 100000
#define EE 3200000
#define GG 512
#define NBK 391    // ceil(NN/256); bucket = node >> 8
#define NHB 256    // histogram blocks
#define ECHUNK 12500  // EE / NHB exactly
#define MLPGRID 1563   // ceil(NN*4/256)
#define NWAVE (MLPGRID * 4)  // 6252 wave slots for stats partials

// ---------- detection ----------
__global__ __launch_bounds__(256) void detect_kernel(
    const uint_t* __restrict__ xw, const uint_t* __restrict__ ew,
    const uint_t* __restrict__ bw, int* __restrict__ flags)
{
    __shared__ int sb[256], se[256], sbb[256];
    int t = threadIdx.x;
    uint_t w = xw[t];
    uint_t eL = (w >> 7) & 0xffu;
    sb[t] = (eL >= 112u && eL <= 135u) ? 1 : 0;
    se[t] = (ew[2 * t + 1] == 0u) ? 1 : 0;
    sbb[t] = (bw[NN - 512 + 2 * t + 1] == 0u) ? 1 : 0;
    __syncthreads();
    for (int off = 128; off > 0; off >>= 1) {
        if (t < off) { sb[t] += sb[t + off]; se[t] += se[t + off]; sbb[t] += sbb[t + off]; }
        __syncthreads();
    }
    if (t == 0) {
        flags[0] = (sb[0] < 128) ? 1 : 0;   // 1 => fp32 floats
        flags[1] = (se[0] >= 128) ? 1 : 0;  // 1 => int64 edges
        flags[2] = (sbb[0] >= 128) ? 1 : 0; // 1 => int64 batch
    }
}

// ---------- canonicalization ----------
__global__ __launch_bounds__(256) void cvt_w_kernel(
    const void* __restrict__ W1, const void* __restrict__ b1,
    const void* __restrict__ W2, const void* __restrict__ b2,
    const void* __restrict__ g, const void* __restrict__ be,
    const int* __restrict__ flags, float* __restrict__ wf)
{
    int i = blockIdx.x * 256 + threadIdx.x;
    if (i >= 33792) return;
    const void* src; int off;
    if (i < 16384)      { src = W1; off = i; }
    else if (i < 32768) { src = W2; off = i - 16384; }
    else if (i < 33024) { src = b1; off = i - 32768; }
    else if (i < 33280) { src = b2; off = i - 33024; }
    else if (i < 33536) { src = g;  off = i - 33280; }
    else                { src = be; off = i - 33536; }
    float v = flags[0] ? ((const float*)src)[off]
                       : __bfloat162float(((const __hip_bfloat16*)src)[off]);
    wf[i] = v;
}

__global__ __launch_bounds__(256) void cvt_x_kernel(
    const void* __restrict__ x, const int* __restrict__ flags,
    float* __restrict__ zA, ushort_t* __restrict__ zb, int total)
{
    int i = blockIdx.x * 256 + threadIdx.x;
    if (i >= total) return;
    float v;
    ushort_t bits;
    if (flags[0]) {
        v = ((const float*)x)[i];
        __hip_bfloat16 b = __float2bfloat16(v);
        bits = *(ushort_t*)&b;
    } else {
        bits = ((const ushort_t*)x)[i];
        uint_t u = (uint_t)bits << 16;
        v = __uint_as_float(u);
    }
    zA[i] = v;
    zb[i] = bits;
}

// batch is SORTED: zero-atomic group offsets via boundary detection.
// gstart[g] (G+1 entries) = first index i with batch[i] >= g.
__global__ __launch_bounds__(256) void cvt_batch_kernel(
    const int* __restrict__ bw, const int* __restrict__ flags,
    int* __restrict__ b32, int* __restrict__ gstart, int n)
{
    int i = blockIdx.x * 256 + threadIdx.x;
    if (i >= n) return;
    int i64 = flags[2];
    int v = i64 ? bw[2 * i] : bw[i];
    b32[i] = v;
    int vn = (i + 1 < n) ? (i64 ? bw[2 * (i + 1)] : bw[i + 1]) : GG;
    if (i == 0) {
        for (int g = 0; g <= v; ++g) gstart[g] = 0;
    }
    if (vn != v) {
        for (int g = v + 1; g <= vn; ++g) gstart[g] = i + 1;
    }
}

// ---------- atomic-free CSR build (round 9, unchanged) ----------
__global__ __launch_bounds__(256) void count_hist_kernel(
    const int* __restrict__ ei, const int* __restrict__ flags,
    int* __restrict__ histo, int E)
{
    __shared__ int lh[NBK];
    int b = blockIdx.x, t = threadIdx.x;
    for (int j = t; j < NBK; j += 256) lh[j] = 0;
    __syncthreads();
    int i64 = flags[1];
    int e0 = b * ECHUNK, e1 = min(e0 + ECHUNK, E);
    for (int i = e0 + t; i < e1; i += 256) {
        int d = i64 ? ei[2 * (E + i)] : ei[E + i];
        atomicAdd(&lh[d >> 8], 1);
    }
    __syncthreads();
    for (int j = t; j < NBK; j += 256) histo[j * NHB + b] = lh[j];
}

__global__ __launch_bounds__(NHB) void blockscan_kernel(
    int* __restrict__ histo, int* __restrict__ tot)
{
    __shared__ int sd[NHB];
    int j = blockIdx.x, t = threadIdx.x;
    int v = histo[j * NHB + t];
    sd[t] = v;
    __syncthreads();
    #pragma unroll
    for (int off = 1; off < NHB; off <<= 1) {
        int add = (t >= off) ? sd[t - off] : 0;
        __syncthreads();
        sd[t] += add;
        __syncthreads();
    }
    histo[j * NHB + t] = sd[t] - v;
    if (t == NHB - 1) tot[j] = sd[NHB - 1];
}

__global__ __launch_bounds__(512) void bscan_kernel(
    const int* __restrict__ tot, int* __restrict__ bktoff)
{
    __shared__ int sd[512];
    int t = threadIdx.x;
    int v = (t < NBK) ? tot[t] : 0;
    sd[t] = v;
    __syncthreads();
    #pragma unroll
    for (int off = 1; off < 512; off <<= 1) {
        int add = (t >= off) ? sd[t - off] : 0;
        __syncthreads();
        sd[t] += add;
        __syncthreads();
    }
    if (t < NBK) bktoff[t] = sd[t] - v;
    if (t == 511) bktoff[NBK] = sd[511];
}

__global__ __launch_bounds__(256) void pair_scatter_kernel(
    const int* __restrict__ ei, const int* __restrict__ flags,
    const int* __restrict__ histo, const int* __restrict__ bktoff,
    int2* __restrict__ pairs, int E)
{
    __shared__ int cur[NBK];
    int b = blockIdx.x, t = threadIdx.x;
    for (int j = t; j < NBK; j += 256) cur[j] = histo[j * NHB + b] + bktoff[j];
    __syncthreads();
    int i64 = flags[1];
    int e0 = b * ECHUNK, e1 = min(e0 + ECHUNK, E);
    for (int i = e0 + t; i < e1; i += 256) {
        int d = i64 ? ei[2 * (E + i)] : ei[E + i];
        int s = i64 ? ei[2 * i]       : ei[i];
        int p = atomicAdd(&cur[d >> 8], 1);
        pairs[p] = make_int2(d, s);
    }
}

__global__ __launch_bounds__(256) void bucket_deg_kernel(
    const int2* __restrict__ pairs, const int* __restrict__ bktoff,
    int* __restrict__ deg, int N)
{
    __shared__ int cnt[256];
    int j = blockIdx.x, t = threadIdx.x;
    cnt[t] = 0;
    __syncthreads();
    int e0 = bktoff[j], e1 = bktoff[j + 1];
    for (int i = e0 + t; i < e1; i += 256)
        atomicAdd(&cnt[pairs[i].x & 255], 1);
    __syncthreads();
    int idx = j * 256 + t;
    if (idx < N) deg[idx] = cnt[t];
}

__global__ __launch_bounds__(256) void scan1_kernel(
    const int* __restrict__ deg, int* __restrict__ part, int* __restrict__ bsum, int n)
{
    __shared__ int sd[256];
    int t = threadIdx.x;
    int i0 = blockIdx.x * 1024 + t * 4;
    int v0 = 0, v1 = 0, v2 = 0, v3 = 0;
    if (i0 + 3 < n) {
        int4 v = *(const int4*)(deg + i0);
        v0 = v.x; v1 = v.y; v2 = v.z; v3 = v.w;
    } else if (i0 < n) {
        v0 = deg[i0];
        if (i0 + 1 < n) v1 = deg[i0 + 1];
        if (i0 + 2 < n) v2 = deg[i0 + 2];
    }
    int s = v0 + v1 + v2 + v3;
    sd[t] = s;
    __syncthreads();
    #pragma unroll
    for (int off = 1; off < 256; off <<= 1) {
        int add = (t >= off) ? sd[t - off] : 0;
        __syncthreads();
        sd[t] += add;
        __syncthreads();
    }
    int incl = sd[t];
    int e0 = incl - s;
    int p0 = e0 + v0, p1 = p0 + v1, p2 = p1 + v2, p3 = p2 + v3;
    if (i0 < n)     part[i0]     = p0;
    if (i0 + 1 < n) part[i0 + 1] = p1;
    if (i0 + 2 < n) part[i0 + 2] = p2;
    if (i0 + 3 < n) part[i0 + 3] = p3;
    if (t == 255) bsum[blockIdx.x] = incl;
}

__global__ __launch_bounds__(128) void scan2_kernel(int* __restrict__ bsum, int nb)
{
    __shared__ int sd[128];
    int t = threadIdx.x;
    int own = (t < nb) ? bsum[t] : 0;
    sd[t] = own;
    __syncthreads();
    #pragma unroll
    for (int off = 1; off < 128; off <<= 1) {
        int add = (t >= off) ? sd[t - off] : 0;
        __syncthreads();
        sd[t] += add;
        __syncthreads();
    }
    if (t < nb) bsum[t] = sd[t] - own;
}

__global__ __launch_bounds__(256) void scan3_kernel(
    const int* __restrict__ part, const int* __restrict__ bsum,
    const int* __restrict__ deg, int* __restrict__ indptr,
    float* __restrict__ inv_deg, int n)
{
    int i = blockIdx.x * 256 + threadIdx.x;
    if (i >= n) return;
    int val = part[i] + bsum[i >> 10];
    indptr[i + 1] = val;
    int d = deg[i];
    inv_deg[i] = (d > 0) ? 1.0f / (float)d : 0.0f;
    if (i == 0) indptr[0] = 0;
}

// invg from sorted-boundary gstart + identity-init of ac slot 0 (A=1, C=0)
__global__ __launch_bounds__(512) void invg_kernel(
    const int* __restrict__ gstart, float* __restrict__ invg,
    float* __restrict__ ac, int G)
{
    int g = threadIdx.x;
    if (g < G) {
        int c = gstart[g + 1] - gstart[g];
        invg[g] = (c > 0) ? 1.0f / (float)c : 0.0f;
    }
    if (g < 64) ac[g] = 1.0f;
    else if (g < 128) ac[g] = 0.0f;
}

__global__ __launch_bounds__(256) void csr_fill_kernel(
    const int2* __restrict__ pairs, const int* __restrict__ bktoff,
    const int* __restrict__ indptr, int* __restrict__ esrc, int N)
{
    __shared__ int cur[256];
    int j = blockIdx.x, t = threadIdx.x;
    int idx = j * 256 + t;
    cur[t] = (idx < N) ? indptr[idx] : 0;
    __syncthreads();
    int e0 = bktoff[j], e1 = bktoff[j + 1];
    for (int i = e0 + t; i < e1; i += 256) {
        int2 e = pairs[i];
        int p = atomicAdd(&cur[e.x & 255], 1);
        esrc[p] = e.y;
    }
}

// ---------- per-layer ----------
// agg: edge-index broadcast, explicit 16-deep gather batches (round-14 form).
// zout = A*(z_own + mean(z_nb)) + C*(1+[deg>0]); A,C from the ac slot.
__global__ __launch_bounds__(256) void agg_kernel(
    const float* __restrict__ zprev, const ushort_t* __restrict__ zb,
    const int* __restrict__ indptr, const int* __restrict__ esrc,
    const float* __restrict__ inv_deg, const float* __restrict__ ac,
    float* __restrict__ zout, int n)
{
    int t = threadIdx.x;
    int grp = t >> 4, l = t & 15;
    int lane = t & 63;
    int gl0 = lane & 48;
    int node = blockIdx.x * 16 + grp;
    if (node >= n) return;
    int e0 = indptr[node], e1 = indptr[node + 1];
    // hoisted independent loads: overlap with the gather loop
    float idg = inv_deg[node];
    float4 own = *(const float4*)(zprev + (size_t)node * 64 + l * 4);
    float4 A = *(const float4*)(ac + l * 4);
    float4 C = *(const float4*)(ac + 64 + l * 4);
    float a0 = 0.f, a1 = 0.f, a2 = 0.f, a3 = 0.f;
    const ushort_t* zbl = zb + l * 4;

    int base = e0;
    // full chunks: 16 gathers batched (issue loop separate from accumulate)
    for (; base + 16 <= e1; base += 16) {
        int myi = esrc[base + l];
        uint2 vv[16];
        #pragma unroll
        for (int j = 0; j < 16; ++j) {
            int s = __shfl(myi, gl0 + j, 64);
            vv[j] = *(const uint2*)(zbl + (size_t)s * 64);
        }
        #pragma unroll
        for (int j = 0; j < 16; ++j) {
            a0 += __uint_as_float(vv[j].x << 16);
            a1 += __uint_as_float(vv[j].x & 0xffff0000u);
            a2 += __uint_as_float(vv[j].y << 16);
            a3 += __uint_as_float(vv[j].y & 0xffff0000u);
        }
    }
    // remainder: masked 16-wide batch; pad lanes re-read edge-0's row (L1 hit)
    // and are forced to +0.0f => accumulation chain is bit-identical.
    int cnt = e1 - base;
    if (cnt > 0) {
        int myi = (l < cnt) ? esrc[base + l] : 0;
        uint2 vv[16];
        #pragma unroll
        for (int j = 0; j < 16; ++j) {
            int jj = (j < cnt) ? j : 0;
            int s = __shfl(myi, gl0 + jj, 64);
            uint2 v = *(const uint2*)(zbl + (size_t)s * 64);
            vv[j].x = (j < cnt) ? v.x : 0u;
            vv[j].y = (j < cnt) ? v.y : 0u;
        }
        #pragma unroll
        for (int j = 0; j < 16; ++j) {
            a0 += __uint_as_float(vv[j].x << 16);
            a1 += __uint_as_float(vv[j].x & 0xffff0000u);
            a2 += __uint_as_float(vv[j].y << 16);
            a3 += __uint_as_float(vv[j].y & 0xffff0000u);
        }
    }

    float cf = (idg > 0.f) ? 2.f : 1.f;
    float4 r;
    r.x = fmaf(A.x, fmaf(idg, a0, own.x), C.x * cf);
    r.y = fmaf(A.y, fmaf(idg, a1, own.y), C.y * cf);
    r.z = fmaf(A.z, fmaf(idg, a2, own.z), C.z * cf);
    r.w = fmaf(A.w, fmaf(idg, a3, own.w), C.w * cf);
    *(float4*)(zout + (size_t)node * 64 + l * 4) = r;
}

// MLP: 4 lanes per node, each owns 16 features. Shared operands broadcast
// via __shfl within the 4-lane group; same k-order FMA chain as round 10.
// Round 16: epilogue butterfly -> per-WAVE partial stores (no atomics).
__global__ __launch_bounds__(256, 2) void mlp_kernel(
    float* __restrict__ zf, ushort_t* __restrict__ zb,
    const float* __restrict__ W1f, const float* __restrict__ b1f,
    const float* __restrict__ W2f, const float* __restrict__ b2f,
    float* __restrict__ partials, int n)
{
    __shared__ float w1s[4096];
    __shared__ float w2s[4096];
    __shared__ float bs[128];
    int t = threadIdx.x;
    for (int i = t; i < 4096; i += 256) {
        w1s[i] = W1f[i];
        w2s[i] = W2f[i];
    }
    if (t < 64) bs[t] = b1f[t];
    else if (t < 128) bs[t] = b2f[t - 64];
    __syncthreads();

    int idx = blockIdx.x * 256 + t;
    int node = idx >> 2;
    bool valid = node < n;          // no early return: all lanes join the butterfly
    int sub = t & 3;
    int lane = t & 63;
    int grp = lane & ~3;          // base lane of my 4-lane group
    int j0 = sub * 16;
    float* zrow = zf + (size_t)node * 64;
    ushort_t* zbrow = zb + (size_t)node * 64;

    // my quarter of z
    float zc[16];
    if (valid) {
        const float4* zp = (const float4*)(zrow + j0);
        #pragma unroll
        for (int q = 0; q < 4; ++q) {
            float4 v = zp[q];
            zc[4*q] = v.x; zc[4*q+1] = v.y; zc[4*q+2] = v.z; zc[4*q+3] = v.w;
        }
    } else {
        #pragma unroll
        for (int q = 0; q < 16; ++q) zc[q] = 0.f;
    }

    // GEMM1: y[j0..j0+16)
    float y[16];
    #pragma unroll
    for (int q = 0; q < 16; ++q) y[q] = bs[j0 + q];
    #pragma unroll
    for (int k = 0; k < 64; ++k) {
        float a = __shfl(zc[k & 15], grp + (k >> 4), 64);
        const float4* w = (const float4*)(w1s + k * 64 + j0);
        #pragma unroll
        for (int q = 0; q < 4; ++q) {
            float4 wv = w[q];
            y[4*q]   = fmaf(a, wv.x, y[4*q]);
            y[4*q+1] = fmaf(a, wv.y, y[4*q+1]);
            y[4*q+2] = fmaf(a, wv.z, y[4*q+2]);
            y[4*q+3] = fmaf(a, wv.w, y[4*q+3]);
        }
    }
    #pragma unroll
    for (int q = 0; q < 16; ++q) y[q] = fmaxf(y[q], 0.f);

    // GEMM2: o[j0..j0+16)
    float o[16];
    #pragma unroll
    for (int q = 0; q < 16; ++q) o[q] = bs[64 + j0 + q];
    #pragma unroll
    for (int k = 0; k < 64; ++k) {
        float a = __shfl(y[k & 15], grp + (k >> 4), 64);
        const float4* w = (const float4*)(w2s + k * 64 + j0);
        #pragma unroll
        for (int q = 0; q < 4; ++q) {
            float4 wv = w[q];
            o[4*q]   = fmaf(a, wv.x, o[4*q]);
            o[4*q+1] = fmaf(a, wv.y, o[4*q+1]);
            o[4*q+2] = fmaf(a, wv.z, o[4*q+2]);
            o[4*q+3] = fmaf(a, wv.w, o[4*q+3]);
        }
    }

    // outer relu
    float h[16];
    #pragma unroll
    for (int q = 0; q < 16; ++q) h[q] = fmaxf(o[q], 0.f);

    // store fp32 + bf16 mirror (group-contiguous)
    if (valid) {
        #pragma unroll
        for (int q = 0; q < 4; ++q) {
            float4 v;
            v.x = h[4*q]; v.y = h[4*q+1]; v.z = h[4*q+2]; v.w = h[4*q+3];
            *(float4*)(zrow + j0 + q * 4) = v;
            __hip_bfloat16 p0 = __float2bfloat16(v.x);
            __hip_bfloat16 p1 = __float2bfloat16(v.y);
            __hip_bfloat16 p2 = __float2bfloat16(v.z);
            __hip_bfloat16 p3 = __float2bfloat16(v.w);
            uint2 pw;
            pw.x = (uint_t)*(ushort_t*)&p0 | ((uint_t)*(ushort_t*)&p1 << 16);
            pw.y = (uint_t)*(ushort_t*)&p2 | ((uint_t)*(ushort_t*)&p3 << 16);
            *(uint2*)(zbrow + j0 + q * 4) = pw;
        }
    }

    // ---- fused BN stats: butterfly over the 16 lanes sharing sub ----
    float qs[16];
    #pragma unroll
    for (int q = 0; q < 16; ++q) {
        float hv = valid ? h[q] : 0.f;
        h[q] = hv;
        qs[q] = hv * hv;
    }
    #pragma unroll
    for (int m = 4; m <= 32; m <<= 1) {
        #pragma unroll
        for (int q = 0; q < 16; ++q) {
            h[q]  += __shfl_xor(h[q],  m, 64);
            qs[q] += __shfl_xor(qs[q], m, 64);
        }
    }
    // lanes 0..3 hold the per-wave sums for features j0..j0+15.
    // Plain stores to a unique per-wave slot — zero contention, no barrier.
    if ((lane >> 2) == 0) {
        int wid = idx >> 6;   // global wave id, 0..NWAVE-1
        #pragma unroll
        for (int q = 0; q < 16; ++q) {
            partials[(size_t)(j0 + q) * NWAVE + wid]      = h[q];
            partials[(size_t)(64 + j0 + q) * NWAVE + wid] = qs[q];
        }
    }
}

// reduce per-wave partials -> BN affine (A,C) for this layer's ac slot.
// 64 blocks: block f reduces feature f (sum) and 64+f (sumsq).
__global__ __launch_bounds__(256) void redstats_kernel(
    const float* __restrict__ partials, const float* __restrict__ gammaf,
    const float* __restrict__ betaf, float* __restrict__ ac_out)
{
    __shared__ float s1[256], s2[256];
    int f = blockIdx.x;
    int t = threadIdx.x;
    const float* ph = partials + (size_t)f * NWAVE;
    const float* pq = partials + (size_t)(64 + f) * NWAVE;
    float a = 0.f, b = 0.f;
    for (int i = t; i < NWAVE; i += 256) { a += ph[i]; b += pq[i]; }
    s1[t] = a; s2[t] = b;
    __syncthreads();
    for (int off = 128; off > 0; off >>= 1) {
        if (t < off) { s1[t] += s1[t + off]; s2[t] += s2[t + off]; }
        __syncthreads();
    }
    if (t == 0) {
        const float invN = 1.0f / (float)NN;
        float mu = s1[0] * invN;
        float var = s2[0] * invN - mu * mu;
        if (var < 0.f) var = 0.f;
        float A = gammaf[f] * rsqrtf(var + 1e-5f);
        float C = betaf[f] - mu * A;
        ac_out[f] = A;
        ac_out[64 + f] = C;
    }
}

// pools only: h = A*z + C on the fly; node_pool (+=), gpool run-length atomics.
__global__ __launch_bounds__(256) void pool_kernel(
    const float* __restrict__ z, float* __restrict__ node_pool,
    const int* __restrict__ b32, const float* __restrict__ ac,
    float* __restrict__ gpool, int N, int first)
{
    int wave = (blockIdx.x * 256 + threadIdx.x) >> 6;
    int f = threadIdx.x & 63;
    int n0 = wave * 16;
    if (n0 >= N) return;
    int n1 = min(n0 + 16, N);
    float A = ac[f], C = ac[64 + f];
    float racc = 0.f;
    int cur = b32[n0];
    int n = n0;
    for (; n + 4 <= n1; n += 4) {
        int4 gv = *(const int4*)(b32 + n);
        size_t idx = (size_t)n * 64 + f;
        // 4 independent loads in flight
        float z0 = z[idx];
        float z1 = z[idx + 64];
        float z2 = z[idx + 128];
        float z3 = z[idx + 192];
        float h0 = fmaf(z0, A, C);
        float h1 = fmaf(z1, A, C);
        float h2 = fmaf(z2, A, C);
        float h3 = fmaf(z3, A, C);
        if (first) {
            node_pool[idx]       = h0;
            node_pool[idx + 64]  = h1;
            node_pool[idx + 128] = h2;
            node_pool[idx + 192] = h3;
        } else {
            float p0 = node_pool[idx];
            float p1 = node_pool[idx + 64];
            float p2 = node_pool[idx + 128];
            float p3 = node_pool[idx + 192];
            node_pool[idx]       = p0 + h0;
            node_pool[idx + 64]  = p1 + h1;
            node_pool[idx + 128] = p2 + h2;
            node_pool[idx + 192] = p3 + h3;
        }
        // run-length gpool accumulation, original per-node order
        int gs0 = gv.x, gs1 = gv.y, gs2 = gv.z, gs3 = gv.w;
        if (gs0 != cur) { atomicAdd(&gpool[(size_t)cur * 64 + f], racc); racc = 0.f; cur = gs0; }
        racc += h0;
        if (gs1 != cur) { atomicAdd(&gpool[(size_t)cur * 64 + f], racc); racc = 0.f; cur = gs1; }
        racc += h1;
        if (gs2 != cur) { atomicAdd(&gpool[(size_t)cur * 64 + f], racc); racc = 0.f; cur = gs2; }
        racc += h2;
        if (gs3 != cur) { atomicAdd(&gpool[(size_t)cur * 64 + f], racc); racc = 0.f; cur = gs3; }
        racc += h3;
    }
    for (; n < n1; ++n) {  // tail (unused when 16 | N; kept for safety)
        int g = b32[n];
        if (g != cur) { atomicAdd(&gpool[(size_t)cur * 64 + f], racc); racc = 0.f; cur = g; }
        size_t idx = (size_t)n * 64 + f;
        float hv = fmaf(z[idx], A, C);
        float np = first ? hv : (node_pool[idx] + hv);
        node_pool[idx] = np;
        racc += hv;
    }
    atomicAdd(&gpool[(size_t)cur * 64 + f], racc);
}

__global__ __launch_bounds__(256) void finalize_kernel(
    const float* __restrict__ node_pool, const float* __restrict__ gpool,
    const float* __restrict__ invg, const int* __restrict__ flags,
    void* __restrict__ out, int N)
{
    int i = blockIdx.x * 256 + threadIdx.x;
    int nd = N * 64;
    int total = nd + GG * 64;
    if (i >= total) return;
    float v;
    if (i < nd) v = node_pool[i];
    else { int j = i - nd; v = gpool[j] * invg[j >> 6]; }
    if (flags[0]) ((float*)out)[i] = v;
    else ((__hip_bfloat16*)out)[i] = __float2bfloat16(v);
}

extern "C" void kernel_launch(void* const* d_in, const int* in_sizes, int n_in,
                              void* d_out, int out_size, void* d_ws, size_t ws_size,
                              hipStream_t stream)
{
    constexpr int N = NN, E = EE, G = GG;
    constexpr int ND = N * 64;

    const void* x     = d_in[0];
    const void* W1    = d_in[1];
    const void* b1    = d_in[2];
    const void* W2    = d_in[3];
    const void* b2    = d_in[4];
    const void* gamma = d_in[5];
    const void* beta  = d_in[6];
    const int* ei     = (const int*)d_in[7];
    const int* batw   = (const int*)d_in[8];

    char* p = (char*)d_ws;
    auto alloc = [&](size_t bytes) -> char* {
        char* r = p;
        p += (bytes + 255) & ~(size_t)255;
        return r;
    };
    float*    zbufA     = (float*)alloc((size_t)ND * 4);
    float*    zbufB     = (float*)alloc((size_t)ND * 4);
    float*    node_pool = (float*)alloc((size_t)ND * 4);
    ushort_t* zb        = (ushort_t*)alloc((size_t)ND * 2);
    int*      esrc      = (int*)alloc((size_t)E * 4);
    int*      indptr    = (int*)alloc((size_t)(N + 1) * 4);
    int*      deg       = (int*)alloc((size_t)N * 4);
    int*      part      = (int*)alloc((size_t)N * 4);
    float*    invdeg    = (float*)alloc((size_t)N * 4);
    int*      b32       = (int*)alloc((size_t)N * 4);
    int*      bsum      = (int*)alloc(128 * 4);
    int*      gstart    = (int*)alloc((size_t)(G + 1) * 4);
    float*    invg      = (float*)alloc(G * 4);
    float*    gpool     = (float*)alloc((size_t)G * 64 * 4);
    float*    ac5       = (float*)alloc(5 * 128 * 4);  // slot0 identity, slots1..4 BN_l
    float*    partials  = (float*)alloc((size_t)128 * NWAVE * 4);  // 3.2 MB
    float*    wf        = (float*)alloc(33792 * 4);
    int*      flags     = (int*)alloc(16 * 4);
    int*      histo     = (int*)alloc((size_t)NBK * NHB * 4);
    int*      tot       = (int*)alloc((size_t)NBK * 4);
    int*      bktoff    = (int*)alloc((size_t)(NBK + 1) * 4);
    // pairs aliases node_pool: dead until first pool_kernel; E*8 == ND*4 bytes
    int2*     pairs     = (int2*)node_pool;

    hipMemsetAsync(gpool, 0, (size_t)G * 64 * 4, stream);

    detect_kernel<<<1, 256, 0, stream>>>(
        (const uint_t*)x, (const uint_t*)ei, (const uint_t*)batw, flags);
    cvt_w_kernel<<<132, 256, 0, stream>>>(W1, b1, W2, b2, gamma, beta, flags, wf);
    cvt_x_kernel<<<(ND + 255) / 256, 256, 0, stream>>>(x, flags, zbufA, zb, ND);
    cvt_batch_kernel<<<(N + 255) / 256, 256, 0, stream>>>(batw, flags, b32, gstart, N);
    count_hist_kernel<<<NHB, 256, 0, stream>>>(ei, flags, histo, E);
    blockscan_kernel<<<NBK, NHB, 0, stream>>>(histo, tot);
    bscan_kernel<<<1, 512, 0, stream>>>(tot, bktoff);
    pair_scatter_kernel<<<NHB, 256, 0, stream>>>(ei, flags, histo, bktoff, pairs, E);
    bucket_deg_kernel<<<NBK, 256, 0, stream>>>(pairs, bktoff, deg, N);
    int nb = (N + 1023) / 1024;  // 98
    scan1_kernel<<<nb, 256, 0, stream>>>(deg, part, bsum, N);
    scan2_kernel<<<1, 128, 0, stream>>>(bsum, nb);
    scan3_kernel<<<(N + 255) / 256, 256, 0, stream>>>(part, bsum, deg, indptr, invdeg, N);
    invg_kernel<<<1, 512, 0, stream>>>(gstart, invg, ac5, G);
    csr_fill_kernel<<<NBK, 256, 0, stream>>>(pairs, bktoff, indptr, esrc, N);

    float* zin = zbufA;
    float* zout = zbufB;
    for (int l = 0; l < 4; ++l) {
        agg_kernel<<<(N + 15) / 16, 256, 0, stream>>>(
            zin, zb, indptr, esrc, invdeg, ac5 + l * 128, zout, N);
        mlp_kernel<<<MLPGRID, 256, 0, stream>>>(
            zout, zb, wf + l * 4096, wf + 32768 + l * 64,
            wf + 16384 + l * 4096, wf + 33024 + l * 64,
            partials, N);
        redstats_kernel<<<64, 256, 0, stream>>>(
            partials, wf + 33280 + l * 64, wf + 33536 + l * 64,
            ac5 + (l + 1) * 128);
        pool_kernel<<<(N + 63) / 64, 256, 0, stream>>>(
            zout, node_pool, b32, ac5 + (l + 1) * 128, gpool, N, (l == 0) ? 1 : 0);
        float* tmp = zin; zin = zout; zout = tmp;
    }
    finalize_kernel<<<(ND + G * 64 + 255) / 256, 256, 0, stream>>>(
        node_pool, gpool, invg, flags, d_out, N);
}